// Round 14
// baseline (728.318 us; speedup 1.0000x reference)
//
#include <hip/hip_runtime.h>

// TemporalGAT: LSTM(T=64,H=128) -> ReLU -> GCNConv -> ReLU -> GATConv(3x64) -> mean
// Round 28:
// (1) degdinv kernel ELIMINATED: deg accumulated by atomicAdd in the HIDDEN
//     bucket build (free under the LSTM, r25), zeroed in prep; the fused agg
//     kernel computes rsqrt(deg+1) on the fly (1 trans op/edge, same 4B
//     gather). 7 -> 6 launches.
// (2) LSTM split-wait: step start no longer blocks on the partner's WHOLE
//     previous step. Partner's h lands in two banks at different times
//     (first bank after its PHASE4(1), body 2). New mid-step signal flWh;
//     body 0 reads own banks immediately, MFMAs them, waits flWh for
//     partner bank A, flW for bank B, then signals flR (after both reads,
//     so the overwrite gate is unchanged). Symmetric orders per role
//     (0,1,2,3 / 2,3,0,1). Overlaps my early MFMAs with partner tail
//     phase4s (~25% of the step). If flat: handshake is proven not the
//     stall and the LSTM is at its structural floor.

#define N_NODES 20000
#define T_STEPS 64
#define N_EDGES 640000
#define HDIM    128
#define JOUT    192   // HEADS*OUT = 3*64
#define NEG_SLOPE 0.2f
#define EDGE_CAP 128  // bucket slots per node (fixed input: max degree ~65)
#define NBW     16    // nodes per group
#define NGRP    5
#define NBB     (NBW * NGRP)   // 80 nodes per block
#define BTHR    640            // 10 waves: 5 groups x 2 roles
#define NBLK    250            // LSTM blocks; blocks NBLK..GRIDX-1 build buckets
#define GRIDX   256
#define LDS_W     131072                  // packed Whh fp16
#define LDS_BW    4096                    // (bias, wih) float2[512]
#define LDS_SCR   (NGRP * 4096)           // per-group h scratch
#define LDS_FLG   256                     // pair-sync flags (flR, flW, flWh)
#define LDS_TOTAL (LDS_W + LDS_BW + LDS_SCR + LDS_FLG)   // 155904

#define L2E  1.4426950408889634f
#define K2E  2.8853900817779268f   // 2*log2(e)

typedef _Float16 half8 __attribute__((ext_vector_type(8)));
typedef _Float16 half4v __attribute__((ext_vector_type(4)));
typedef _Float16 half2v __attribute__((ext_vector_type(2)));
typedef float floatx4 __attribute__((ext_vector_type(4)));

__device__ __forceinline__ float lrelu(float x) { return x > 0.f ? x : NEG_SLOPE * x; }

// ---------------------------------------------------------------------------
// prep: pack Whh (exp2-domain scaled), pack gcnW/gatW, zero cnt/deg/Wgt/accum.
__global__ __launch_bounds__(256) void prep_kernel(
    const float* __restrict__ Whh, _Float16* __restrict__ Wpack,
    const float* __restrict__ gcnW, _Float16* __restrict__ WpackG,
    const float* __restrict__ gatW, _Float16* __restrict__ WpackA,
    int* __restrict__ cnt, float* __restrict__ deg,
    float* __restrict__ Wgt, float* __restrict__ accum)
{
  const int b = blockIdx.x;
  const int tid = threadIdx.x;
  if (b < 32) {
    int i = b * 256 + tid;   // 0..8191
    int tile = i >> 6, lane = i & 63;
    int nt = tile >> 2, kt = tile & 3;
    int row = nt * 16 + (lane & 15);
    int c0  = kt * 32 + (lane >> 4) * 8;
    const float sc = ((row >> 7) == 2) ? K2E : L2E;
    half8 v;
    #pragma unroll
    for (int j = 0; j < 8; ++j)
      v[j] = (_Float16)(Whh[row * 128 + c0 + j] * sc);
    *(half8*)&Wpack[(size_t)i * 8] = v;
  } else if (b < 40) {
    int i = (b - 32) * 256 + tid;   // < 2048
    int tile = i >> 6, lane = i & 63;
    int mt = tile >> 2, kt = tile & 3;
    int row = mt * 16 + (lane & 15);
    int c0  = kt * 32 + (lane >> 4) * 8;
    half8 v;
    #pragma unroll
    for (int j = 0; j < 8; ++j) v[j] = (_Float16)gcnW[row * 128 + c0 + j];
    *(half8*)&WpackG[(size_t)i * 8] = v;
  } else if (b < 52) {
    int i = (b - 40) * 256 + tid;   // < 3072
    int tile = i >> 6, lane = i & 63;
    int mt = tile >> 2, kt = tile & 3;
    int row = mt * 16 + (lane & 15);
    int c0  = kt * 32 + (lane >> 4) * 8;
    half8 v;
    #pragma unroll
    for (int j = 0; j < 8; ++j) v[j] = (_Float16)gatW[row * 128 + c0 + j];
    *(half8*)&WpackA[(size_t)i * 8] = v;
  } else {
    int i = (b - 52) * 256 + tid;   // < 20224
    if (i < N_NODES) {
      cnt[i] = 0;
      deg[i] = 0.f;
      *(float4*)&Wgt[i * 4] = make_float4(0.f, 0.f, 0.f, 0.f);
    }
    if (i < JOUT) accum[i] = 0.f;
  }
}

// ---------------------------------------------------------------------------
// LSTM building blocks (L = literal local cg index 0..3).

#define INITACC(L, acc) do {                                                  \
  _Pragma("unroll") for (int g_ = 0; g_ < 4; ++g_) {                          \
    const float4 p0_ = *(const float4*)&bwRole[g_ * 128 + (L) * 16];          \
    const float4 p1_ = *(const float4*)&bwRole[g_ * 128 + (L) * 16 + 2];      \
    acc[g_][0] = p0_.x + xv * p0_.y;                                          \
    acc[g_][1] = p0_.z + xv * p0_.w;                                          \
    acc[g_][2] = p1_.x + xv * p1_.y;                                          \
    acc[g_][3] = p1_.z + xv * p1_.w;                                          \
  }                                                                           \
} while (0)

#define LDA(buf, L, KT) do {                                                  \
  _Pragma("unroll") for (int g_ = 0; g_ < 4; ++g_)                            \
    buf[g_] = *(const half8*)&WlRole[g_ * 16384 + (L) * 2048 + (KT) * 512];   \
} while (0)

#define MFA(acc, buf, KT) do {                                                \
  _Pragma("unroll") for (int g_ = 0; g_ < 4; ++g_)                            \
    acc[g_] = __builtin_amdgcn_mfma_f32_16x16x32_f16(                         \
        buf[g_], Bf[(KT)], acc[g_], 0, 0, 0);                                 \
} while (0)

#define PHASE4(L, acc) do {                                                   \
  const int cg_ = cgb + (L);                                                  \
  half4v hpack;                                                               \
  _Pragma("unroll") for (int r_ = 0; r_ < 4; ++r_) {                          \
    const float Be = __builtin_amdgcn_exp2f(-acc[0][r_]);                     \
    const float Ae = __builtin_amdgcn_exp2f(-acc[1][r_]);                     \
    const float De = __builtin_amdgcn_exp2f(acc[2][r_]);                      \
    const float Ee = __builtin_amdgcn_exp2f(-acc[3][r_]);                     \
    const float Ap = Ae + 1.f;                                                \
    const float Bp = Be + 1.f;                                                \
    const float Dp = De + 1.f;                                                \
    const float Nn = cst[(L) * 4 + r_] * Bp * Dp + Ap * (De - 1.f);           \
    const float cv = Nn * __builtin_amdgcn_rcpf(Ap * Bp * Dp);                \
    cst[(L) * 4 + r_] = cv;                                                   \
    const float cvc = fminf(fmaxf(cv, -10.f), 10.f);                          \
    const float Fe = __builtin_amdgcn_exp2f(K2E * cvc);                       \
    hpack[r_] = (_Float16)((Fe - 1.f) *                                       \
                __builtin_amdgcn_rcpf((Ee + 1.f) * (Fe + 1.f)));              \
  }                                                                           \
  const int lp_ = nl + 16 * (2 * (cg_ & 1) + wq_hi);                          \
  *(half4v*)&myscr[(cg_ >> 1) * 512 + lp_ * 8 + j0] = hpack;                  \
} while (0)

#define SB __builtin_amdgcn_sched_barrier(0)

// Pair-local sync: SIGNAL publishes epoch after a fence; WAITGE spins
// (lane 0) until the partner reaches the epoch, then fences.
#define SIGNAL(arr, val) do {                                                 \
  __threadfence_block();                                                      \
  if (ln == 0) arr[wv] = (val);                                               \
} while (0)
#define WAITGE(arr, val) do {                                                 \
  if (ln == 0) { while (arr[pw] < (val)) __builtin_amdgcn_s_sleep(1); }       \
  __builtin_amdgcn_wave_barrier();                                            \
  __threadfence_block();                                                      \
} while (0)

// One LSTM step. K0,K1 = OWN h banks (written by this role last step --
// program-order safe to read immediately); K2 = partner bank available at
// its mid-step signal flWh; K3 = partner bank available at flW. flR is
// signaled only after BOTH partner-bank reads (overwrite gate unchanged).
#define LSTM_STEP(t, K0, K1, K2, K3) do {                                     \
  half8 Bf[4];                                                                \
  Bf[K0] = *(const half8*)&scrLane[(K0) * 512];                               \
  Bf[K1] = *(const half8*)&scrLane[(K1) * 512];                               \
  floatx4 accA[4], accB[4];                                                   \
  half8 Aa[4], Ab[4];                                                         \
  /* body 0: own-bank MFMAs first, partner banks as they arrive */            \
  INITACC(0, accA);                                                           \
  LDA(Aa, 0, K0); LDA(Ab, 0, K1);                                             \
  MFA(accA, Aa, K0); LDA(Aa, 0, K2);                                          \
  MFA(accA, Ab, K1); LDA(Ab, 0, K3);                                          \
  WAITGE(flWh, (t));                                                          \
  Bf[K2] = *(const half8*)&scrLane[(K2) * 512];                               \
  MFA(accA, Aa, K2);                                                          \
  WAITGE(flW, (t));                                                           \
  Bf[K3] = *(const half8*)&scrLane[(K3) * 512];                               \
  MFA(accA, Ab, K3);                                                          \
  SIGNAL(flR, (t) + 1);                                                       \
  /* body 1 */                                                                \
  INITACC(1, accB); LDA(Aa, 1, 0); LDA(Ab, 1, 1);                             \
  WAITGE(flR, (t) + 1);                                                       \
  SB; PHASE4(0, accA);                                                        \
  MFA(accB, Aa, 0); LDA(Aa, 1, 2);                                            \
  MFA(accB, Ab, 1); LDA(Ab, 1, 3);                                            \
  MFA(accB, Aa, 2); MFA(accB, Ab, 3);                                         \
  /* body 2 */                                                                \
  INITACC(2, accA); LDA(Aa, 2, 0); LDA(Ab, 2, 1);                             \
  SB; PHASE4(1, accB);                                                        \
  SIGNAL(flWh, (t) + 1);  /* first own bank complete */                       \
  MFA(accA, Aa, 0); LDA(Aa, 2, 2);                                            \
  MFA(accA, Ab, 1); LDA(Ab, 2, 3);                                            \
  MFA(accA, Aa, 2); MFA(accA, Ab, 3);                                         \
  /* body 3 */                                                                \
  INITACC(3, accB); LDA(Aa, 3, 0); LDA(Ab, 3, 1);                             \
  SB; PHASE4(2, accA);                                                        \
  MFA(accB, Aa, 0); LDA(Aa, 3, 2);                                            \
  MFA(accB, Ab, 1); LDA(Ab, 3, 3);                                            \
  MFA(accB, Aa, 2); MFA(accB, Ab, 3);                                         \
  PHASE4(3, accB);                                                            \
  SIGNAL(flW, (t) + 1);                                                       \
} while (0)

// ---------------------------------------------------------------------------
// Wave-pair LSTM + hidden bucket build. Blocks 0..NBLK-1: LSTM (10 waves,
// 5 groups x 16 nodes). Blocks NBLK..GRIDX-1: edge-bucket build + deg
// accumulation on the CUs the LSTM leaves idle.
__global__ __attribute__((amdgpu_flat_work_group_size(BTHR, BTHR),
                          amdgpu_waves_per_eu(3, 3)))
void lstm_stream_kernel(
    const float* __restrict__ xfeat, const _Float16* __restrict__ Wpack,
    const float* __restrict__ Wih, const float* __restrict__ bih,
    const float* __restrict__ bhh, _Float16* __restrict__ x1,
    const int* __restrict__ ei, const float* __restrict__ ew,
    int* __restrict__ cnt, int2* __restrict__ pairB, float* __restrict__ deg)
{
  const int tid  = threadIdx.x;   // 0..639

  if (blockIdx.x >= NBLK) {
    // ---- hidden edge-bucket build + deg on otherwise-idle CUs ----
    const int stride = (GRIDX - NBLK) * BTHR;
    for (int e = (blockIdx.x - NBLK) * BTHR + tid; e < N_EDGES; e += stride) {
      const int r = ei[e];
      const int c = ei[N_EDGES + e];
      const float w = ew[e];
      const int p = atomicAdd(&cnt[c], 1);
      pairB[(size_t)c * EDGE_CAP + p] = make_int2(r, __float_as_int(w));
      atomicAdd(&deg[c], w);
    }
    return;
  }

  extern __shared__ char dynlds[];
  _Float16* Wl  = (_Float16*)dynlds;                    // [128 tiles][64 lanes][8]
  float2*   bw  = (float2*)(dynlds + LDS_W);            // [512] (bias, wih) pre-scaled
  _Float16* scr = (_Float16*)(dynlds + LDS_W + LDS_BW); // [5][2048]
  volatile int* flR  = (volatile int*)(dynlds + LDS_W + LDS_BW + LDS_SCR);
  volatile int* flW  = flR + 16;
  volatile int* flWh = flR + 32;

  const int wv   = tid >> 6;      // wave 0..9
  const int pw   = wv ^ 1;        // partner wave
  const int grp  = wv >> 1;       // node group 0..4
  const int role = wv & 1;        // 0: cg0-3, 1: cg4-7
  const int cgb  = role * 4;
  const int ln   = tid & 63;
  const int nl   = ln & 15;       // node within group
  const int quad = ln >> 4;
  const int n0   = blockIdx.x * NBB + grp * NBW;

  // stage packed Whh -> LDS (coalesced float4)
  {
    const float4* src = (const float4*)Wpack;
    float4* dst = (float4*)Wl;
    for (int i = tid; i < LDS_W / 16; i += BTHR) dst[i] = src[i];
  }
  for (int i = tid; i < 512; i += BTHR) {
    const float sc = ((i >> 7) == 2) ? K2E : L2E;
    bw[i] = make_float2((bih[i] + bhh[i]) * sc, Wih[i] * sc);
  }
  {
    float4* z = (float4*)scr;
    for (int i = tid; i < LDS_SCR / 16; i += BTHR)
      z[i] = make_float4(0.f, 0.f, 0.f, 0.f);
  }
  if (tid < 48) { flR[tid] = 0; }
  __syncthreads();   // staging barrier (the only block-wide one)

  _Float16* myscr = scr + grp * 2048;
  const _Float16* WlRole  = Wl + (size_t)cgb * 2048 + (size_t)ln * 8;
  const float2*   bwRole  = bw + cgb * 16 + quad * 4;
  const _Float16* scrLane = myscr + (size_t)ln * 8;
  const float* xrow = xfeat + (size_t)(n0 + nl) * T_STEPS;

  float cst[16];
  #pragma unroll
  for (int i = 0; i < 16; ++i) cst[i] = 0.f;

  const int wq_hi = quad >> 1;
  const int j0    = (quad & 1) * 4;

  float xv = xrow[0];

  // role 0 owns banks 0,1 (cg0-3); role 1 owns banks 2,3 (cg4-7).
  // Partner's first-completed bank: role0's partner(role1) bank 2; role1's
  // partner(role0) bank 0.
  if (role == 0) {
    #pragma unroll 1
    for (int t = 0; t < T_STEPS; ++t) {
      const float xn = xrow[(t + 1 <= 63) ? (t + 1) : 63];
      LSTM_STEP(t, 0, 1, 2, 3);
      xv = xn;
    }
  } else {
    #pragma unroll 1
    for (int t = 0; t < T_STEPS; ++t) {
      const float xn = xrow[(t + 1 <= 63) ? (t + 1) : 63];
      LSTM_STEP(t, 2, 3, 0, 1);
      xv = xn;
    }
  }

  // epilogue: each role reads only its own written banks -> no final sync.
  #pragma unroll
  for (int k = 0; k < 2; ++k) {
    const int kt = role * 2 + k;
    half8 hf = *(const half8*)&scrLane[kt * 512];
    #pragma unroll
    for (int j = 0; j < 8; ++j)
      hf[j] = (_Float16)fmaxf((float)hf[j], 0.f);
    *(half8*)&x1[(size_t)(n0 + nl) * HDIM + kt * 32 + quad * 8] = hf;
  }
}

// ---------------------------------------------------------------------------
// FUSED middle: per block, 16 dest nodes. dinv computed on the fly from deg.
// A: bucket-aggregate x1 rows (4 dest/wave) -> z[16][132] fp16 LDS
// B: z @ gcnW^T + gcnb, relu -> zz (8 M-tiles over 4 waves)
// C: zz @ gatW^T -> xh global + att logits (12 M-tiles over 4 waves)
__global__ __launch_bounds__(256) void agg_gemm_att_kernel(
    const _Float16* __restrict__ x1, const float* __restrict__ deg,
    const int* __restrict__ cnt, const int2* __restrict__ pairB,
    const float* __restrict__ gcn_b,
    const _Float16* __restrict__ PG, const _Float16* __restrict__ PA,
    const float* __restrict__ att_src, const float* __restrict__ att_dst,
    _Float16* __restrict__ xh, float4* __restrict__ asrc,
    float4* __restrict__ adst)
{
  __shared__ float2 stg[4][64];
  __shared__ _Float16 z[16][132];
  __shared__ _Float16 zz[16][132];
  __shared__ float aS[JOUT], aD[JOUT];
  __shared__ float sAp[4][16][3], sDp[4][16][3];

  const int tid = threadIdx.x;
  const int ln = tid & 63;
  const int wv = tid >> 6;
  const int quad = ln >> 4;
  const int nl = ln & 15;
  const int nb = blockIdx.x * 16;

  for (int i = tid; i < JOUT; i += 256) { aS[i] = att_src[i]; aD[i] = att_dst[i]; }

  const half2v* x12 = (const half2v*)x1;
  // phase A: aggregate 4 dest nodes per wave (x1-space; GEMM linearity)
  #pragma unroll 1
  for (int d = 0; d < 4; ++d) {
    const int c = nb + wv * 4 + d;
    const float dc = rsqrtf(deg[c] + 1.0f);
    const half2v xc = x12[c * 64 + ln];
    float ax = (float)xc[0] * dc * dc, ay = (float)xc[1] * dc * dc; // self
    const int cc = cnt[c];
    const size_t base = (size_t)c * EDGE_CAP;
    for (int tb = 0; tb < cc; tb += 64) {
      const int ne = min(64, cc - tb);
      const int k = tb + ln;
      if (k < cc) {
        const int2 pr = pairB[base + k];
        stg[wv][ln] = make_float2(__int_as_float(pr.x),
            __int_as_float(pr.y) * rsqrtf(deg[pr.x] + 1.0f) * dc);
      }
      __builtin_amdgcn_wave_barrier();
      int i = 0;
      for (; i + 4 <= ne; i += 4) {
        float2 p0 = stg[wv][i],     p1 = stg[wv][i + 1];
        float2 p2 = stg[wv][i + 2], p3 = stg[wv][i + 3];
        const half2v a0 = x12[(size_t)__float_as_int(p0.x) * 64 + ln];
        const half2v a1 = x12[(size_t)__float_as_int(p1.x) * 64 + ln];
        const half2v a2 = x12[(size_t)__float_as_int(p2.x) * 64 + ln];
        const half2v a3 = x12[(size_t)__float_as_int(p3.x) * 64 + ln];
        ax += (float)a0[0] * p0.y + (float)a1[0] * p1.y +
              (float)a2[0] * p2.y + (float)a3[0] * p3.y;
        ay += (float)a0[1] * p0.y + (float)a1[1] * p1.y +
              (float)a2[1] * p2.y + (float)a3[1] * p3.y;
      }
      for (; i < ne; ++i) {
        float2 p0 = stg[wv][i];
        const half2v a0 = x12[(size_t)__float_as_int(p0.x) * 64 + ln];
        ax += (float)a0[0] * p0.y; ay += (float)a0[1] * p0.y;
      }
      __builtin_amdgcn_wave_barrier();
    }
    const int dn = wv * 4 + d;
    half2v o; o[0] = (_Float16)ax; o[1] = (_Float16)ay;
    *(half2v*)&z[dn][ln * 2] = o;
  }
  __syncthreads();

  // phase B: z @ gcnW^T -> relu+gcnb -> zz (wave wv: M-tiles 2wv, 2wv+1)
  {
    half8 Bf[4];
    #pragma unroll
    for (int kt = 0; kt < 4; ++kt)
      Bf[kt] = *(const half8*)&z[nl][kt * 32 + quad * 8];
    #pragma unroll
    for (int mm = 0; mm < 2; ++mm) {
      const int m = wv * 2 + mm;
      floatx4 acc = {0.f, 0.f, 0.f, 0.f};
      #pragma unroll
      for (int kt = 0; kt < 4; ++kt) {
        const half8 Af = *(const half8*)&PG[(size_t)((m * 4 + kt) * 64 + ln) * 8];
        acc = __builtin_amdgcn_mfma_f32_16x16x32_f16(Af, Bf[kt], acc, 0, 0, 0);
      }
      #pragma unroll
      for (int j = 0; j < 4; ++j) {
        const int jj = m * 16 + quad * 4 + j;
        zz[nl][jj] = (_Float16)fmaxf(acc[j] + gcn_b[jj], 0.f);
      }
    }
  }
  __syncthreads();

  // phase C: zz @ gatW^T -> xh + att partials (wave wv: M-tiles 3wv..3wv+2)
  {
    half8 Bf[4];
    #pragma unroll
    for (int kt = 0; kt < 4; ++kt)
      Bf[kt] = *(const half8*)&zz[nl][kt * 32 + quad * 8];
    float sA[3] = {0.f, 0.f, 0.f}, sD[3] = {0.f, 0.f, 0.f};
    #pragma unroll
    for (int mm = 0; mm < 3; ++mm) {
      const int m = wv * 3 + mm;
      floatx4 acc = {0.f, 0.f, 0.f, 0.f};
      #pragma unroll
      for (int kt = 0; kt < 4; ++kt) {
        const half8 Af = *(const half8*)&PA[(size_t)((m * 4 + kt) * 64 + ln) * 8];
        acc = __builtin_amdgcn_mfma_f32_16x16x32_f16(Af, Bf[kt], acc, 0, 0, 0);
      }
      const int h  = m >> 2;
      const int jo = (m & 3) * 16 + quad * 4;
      half4v o;
      #pragma unroll
      for (int j = 0; j < 4; ++j) {
        sA[h] += acc[j] * aS[h * 64 + jo + j];
        sD[h] += acc[j] * aD[h * 64 + jo + j];
        o[j] = (_Float16)acc[j];
      }
      *(half4v*)&xh[(size_t)(nb + nl) * JOUT + m * 16 + quad * 4] = o;
    }
    #pragma unroll
    for (int h = 0; h < 3; ++h) {
      sA[h] += __shfl_xor(sA[h], 16); sA[h] += __shfl_xor(sA[h], 32);
      sD[h] += __shfl_xor(sD[h], 16); sD[h] += __shfl_xor(sD[h], 32);
    }
    if (quad == 0) {
      #pragma unroll
      for (int h = 0; h < 3; ++h) {
        sAp[wv][nl][h] = sA[h];
        sDp[wv][nl][h] = sD[h];
      }
    }
  }
  __syncthreads();
  if (tid < 16) {
    float a0 = 0.f, a1 = 0.f, a2 = 0.f, d0 = 0.f, d1 = 0.f, d2 = 0.f;
    #pragma unroll
    for (int w = 0; w < 4; ++w) {
      a0 += sAp[w][tid][0]; a1 += sAp[w][tid][1]; a2 += sAp[w][tid][2];
      d0 += sDp[w][tid][0]; d1 += sDp[w][tid][1]; d2 += sDp[w][tid][2];
    }
    asrc[nb + tid] = make_float4(a0, a1, a2, 0.f);
    adst[nb + tid] = make_float4(d0, d1, d2, 0.f);
  }
}

// ---------------------------------------------------------------------------
// GAT softmax weights (mean-trick): one wave per destination c. Computes
// denom_c per head (single-pass, no max-sub; logits |.|<~4), then scatters
// alpha/denom into per-SOURCE weight sums W[s][h] (+ self term to W[c]).
__global__ __launch_bounds__(256) void gat_weight_kernel(
    const float4* __restrict__ asrc, const float4* __restrict__ adst,
    const int* __restrict__ cnt, const int2* __restrict__ pairB,
    float* __restrict__ W)
{
  const int lane = threadIdx.x & 63;
  const int wv = threadIdx.x >> 6;
  const int c = blockIdx.x * 4 + wv;
  const int cc = cnt[c];
  const size_t base = (size_t)c * EDGE_CAP;
  const float4 adc = adst[c];
  const float4 asc = asrc[c];
  const float se0 = __expf(lrelu(asc.x + adc.x));
  const float se1 = __expf(lrelu(asc.y + adc.y));
  const float se2 = __expf(lrelu(asc.z + adc.z));
  float dp0 = 0.f, dp1 = 0.f, dp2 = 0.f;
  float a0v[2], a1v[2], a2v[2]; int sv[2];
  #pragma unroll
  for (int it = 0; it < 2; ++it) {
    const int k = it * 64 + lane;
    sv[it] = -1;
    a0v[it] = 0.f; a1v[it] = 0.f; a2v[it] = 0.f;
    if (k < cc) {
      const int s = pairB[base + k].x;
      const float4 av = asrc[s];
      const float a0 = __expf(lrelu(av.x + adc.x));
      const float a1 = __expf(lrelu(av.y + adc.y));
      const float a2 = __expf(lrelu(av.z + adc.z));
      dp0 += a0; dp1 += a1; dp2 += a2;
      sv[it] = s; a0v[it] = a0; a1v[it] = a1; a2v[it] = a2;
    }
  }
  #pragma unroll
  for (int off = 1; off < 64; off <<= 1) {
    dp0 += __shfl_xor(dp0, off);
    dp1 += __shfl_xor(dp1, off);
    dp2 += __shfl_xor(dp2, off);
  }
  const float iv0 = 1.f / (dp0 + se0);
  const float iv1 = 1.f / (dp1 + se1);
  const float iv2 = 1.f / (dp2 + se2);
  if (lane == 0) {
    atomicAdd(&W[c * 4 + 0], se0 * iv0);
    atomicAdd(&W[c * 4 + 1], se1 * iv1);
    atomicAdd(&W[c * 4 + 2], se2 * iv2);
  }
  #pragma unroll
  for (int it = 0; it < 2; ++it) {
    if (sv[it] >= 0) {
      atomicAdd(&W[sv[it] * 4 + 0], a0v[it] * iv0);
      atomicAdd(&W[sv[it] * 4 + 1], a1v[it] * iv1);
      atomicAdd(&W[sv[it] * 4 + 2], a2v[it] * iv2);
    }
  }
}

// Final coalesced sweep: accum[j] += sum_s W[s][h] * xh[s][j].
__global__ __launch_bounds__(192) void gat_final_kernel(
    const _Float16* __restrict__ xh, const float* __restrict__ W,
    float* __restrict__ accum)
{
  const int j = threadIdx.x;          // 0..191
  const int h = j >> 6;
  float sum = 0.f;
  const int s0 = blockIdx.x * 80;
  for (int s = s0; s < s0 + 80; ++s)
    sum += W[s * 4 + h] * (float)xh[(size_t)s * JOUT + j];
  atomicAdd(&accum[j], sum);
}

__global__ void finalize_kernel(const float* __restrict__ accum,
                                const float* __restrict__ gat_b,
                                float* __restrict__ out)
{
  int j = threadIdx.x;
  if (j < JOUT) out[j] = accum[j] * (1.0f / N_NODES) + gat_b[j];
}

// ---------------------------------------------------------------------------
extern "C" void kernel_launch(void* const* d_in, const int* in_sizes, int n_in,
                              void* d_out, int out_size, void* d_ws, size_t ws_size,
                              hipStream_t stream)
{
  const float* xfeat = (const float*)d_in[0];
  const int*   eidx  = (const int*)d_in[1];
  const float* eattr = (const float*)d_in[2];
  const float* Wih   = (const float*)d_in[3];
  const float* Whh   = (const float*)d_in[4];
  const float* bihp  = (const float*)d_in[5];
  const float* bhhp  = (const float*)d_in[6];
  const float* gcnW  = (const float*)d_in[7];
  const float* gcnb  = (const float*)d_in[8];
  const float* gatW  = (const float*)d_in[9];
  const float* attS  = (const float*)d_in[10];
  const float* attD  = (const float*)d_in[11];
  const float* gatb  = (const float*)d_in[12];
  float* out = (float*)d_out;

  char* ws = (char*)d_ws;
  size_t off = 0;
  auto alloc = [&](size_t bytes) {
    char* p = ws + off;
    off += (bytes + 255) & ~size_t(255);
    return p;
  };
  _Float16*  x1     = (_Float16*)alloc((size_t)N_NODES * 128 * 2);
  _Float16*  xh     = (_Float16*)alloc((size_t)N_NODES * 192 * 2);
  float4*    asrc   = (float4*)alloc((size_t)N_NODES * 16);
  float4*    adst   = (float4*)alloc((size_t)N_NODES * 16);
  float*     deg    = (float*)alloc((size_t)N_NODES * 4);
  int*       cnt    = (int*)alloc((size_t)N_NODES * 4);
  int2*      pairB  = (int2*)alloc((size_t)N_NODES * EDGE_CAP * 8);
  float*     Wgt    = (float*)alloc((size_t)N_NODES * 4 * 4);
  float*     accum  = (float*)alloc(JOUT * 4);
  _Float16*  wpack  = (_Float16*)alloc(131072);
  _Float16*  wpackG = (_Float16*)alloc((size_t)128 * 128 * 2);
  _Float16*  wpackA = (_Float16*)alloc((size_t)192 * 128 * 2);

  // opt-in to >64KB dynamic LDS for the wave-pair LSTM (idempotent)
  hipFuncSetAttribute((const void*)lstm_stream_kernel,
                      hipFuncAttributeMaxDynamicSharedMemorySize, LDS_TOTAL);

  prep_kernel<<<131, 256, 0, stream>>>(Whh, wpack, gcnW, wpackG, gatW, wpackA,
                                       cnt, deg, Wgt, accum);
  // LSTM (blocks 0..249) + hidden edge-bucket+deg build (blocks 250..255)
  lstm_stream_kernel<<<GRIDX, BTHR, LDS_TOTAL, stream>>>(
      xfeat, wpack, Wih, bihp, bhhp, x1, eidx, eattr, cnt, pairB, deg);
  agg_gemm_att_kernel<<<N_NODES / 16, 256, 0, stream>>>(
      x1, deg, cnt, pairB, gcnb, wpackG, wpackA, attS, attD, xh, asrc, adst);
  gat_weight_kernel<<<N_NODES / 4, 256, 0, stream>>>(asrc, adst, cnt, pairB, Wgt);
  gat_final_kernel<<<N_NODES / 80, 192, 0, stream>>>(xh, Wgt, accum);
  finalize_kernel<<<1, 256, 0, stream>>>(accum, gatb, out);
}

// Round 15
// 724.878 us; speedup vs baseline: 1.0047x; 1.0047x over previous
//
#include <hip/hip_runtime.h>

// TemporalGAT: LSTM(T=64,H=128) -> ReLU -> GCNConv -> ReLU -> GATConv(3x64) -> mean
// Round 29: surgical revert of r28's split-wait regression (LSTM 383->530:
// delaying the flR signal until after partner-bank MFMAs serialized the
// wave pair -- signal placement beats wait placement). Restored r27's
// LSTM_STEP: single WAITGE(flW,t) at step start, flR signaled right after
// the 4 Bf reads. KEPT from r28: deg accumulated by atomicAdd in the
// HIDDEN bucket build (free under the LSTM; WRITE_SIZE confirms), degdinv
// kernel deleted, fused agg computes rsqrt(deg+1) on the fly. 6 launches.

#define N_NODES 20000
#define T_STEPS 64
#define N_EDGES 640000
#define HDIM    128
#define JOUT    192   // HEADS*OUT = 3*64
#define NEG_SLOPE 0.2f
#define EDGE_CAP 128  // bucket slots per node (fixed input: max degree ~65)
#define NBW     16    // nodes per group
#define NGRP    5
#define NBB     (NBW * NGRP)   // 80 nodes per block
#define BTHR    640            // 10 waves: 5 groups x 2 roles
#define NBLK    250            // LSTM blocks; blocks NBLK..GRIDX-1 build buckets
#define GRIDX   256
#define LDS_W     131072                  // packed Whh fp16
#define LDS_BW    4096                    // (bias, wih) float2[512]
#define LDS_SCR   (NGRP * 4096)           // per-group h scratch
#define LDS_FLG   256                     // pair-sync flags (flR, flW)
#define LDS_TOTAL (LDS_W + LDS_BW + LDS_SCR + LDS_FLG)   // 155904

#define L2E  1.4426950408889634f
#define K2E  2.8853900817779268f   // 2*log2(e)

typedef _Float16 half8 __attribute__((ext_vector_type(8)));
typedef _Float16 half4v __attribute__((ext_vector_type(4)));
typedef _Float16 half2v __attribute__((ext_vector_type(2)));
typedef float floatx4 __attribute__((ext_vector_type(4)));

__device__ __forceinline__ float lrelu(float x) { return x > 0.f ? x : NEG_SLOPE * x; }

// ---------------------------------------------------------------------------
// prep: pack Whh (exp2-domain scaled), pack gcnW/gatW, zero cnt/deg/Wgt/accum.
__global__ __launch_bounds__(256) void prep_kernel(
    const float* __restrict__ Whh, _Float16* __restrict__ Wpack,
    const float* __restrict__ gcnW, _Float16* __restrict__ WpackG,
    const float* __restrict__ gatW, _Float16* __restrict__ WpackA,
    int* __restrict__ cnt, float* __restrict__ deg,
    float* __restrict__ Wgt, float* __restrict__ accum)
{
  const int b = blockIdx.x;
  const int tid = threadIdx.x;
  if (b < 32) {
    int i = b * 256 + tid;   // 0..8191
    int tile = i >> 6, lane = i & 63;
    int nt = tile >> 2, kt = tile & 3;
    int row = nt * 16 + (lane & 15);
    int c0  = kt * 32 + (lane >> 4) * 8;
    const float sc = ((row >> 7) == 2) ? K2E : L2E;
    half8 v;
    #pragma unroll
    for (int j = 0; j < 8; ++j)
      v[j] = (_Float16)(Whh[row * 128 + c0 + j] * sc);
    *(half8*)&Wpack[(size_t)i * 8] = v;
  } else if (b < 40) {
    int i = (b - 32) * 256 + tid;   // < 2048
    int tile = i >> 6, lane = i & 63;
    int mt = tile >> 2, kt = tile & 3;
    int row = mt * 16 + (lane & 15);
    int c0  = kt * 32 + (lane >> 4) * 8;
    half8 v;
    #pragma unroll
    for (int j = 0; j < 8; ++j) v[j] = (_Float16)gcnW[row * 128 + c0 + j];
    *(half8*)&WpackG[(size_t)i * 8] = v;
  } else if (b < 52) {
    int i = (b - 40) * 256 + tid;   // < 3072
    int tile = i >> 6, lane = i & 63;
    int mt = tile >> 2, kt = tile & 3;
    int row = mt * 16 + (lane & 15);
    int c0  = kt * 32 + (lane >> 4) * 8;
    half8 v;
    #pragma unroll
    for (int j = 0; j < 8; ++j) v[j] = (_Float16)gatW[row * 128 + c0 + j];
    *(half8*)&WpackA[(size_t)i * 8] = v;
  } else {
    int i = (b - 52) * 256 + tid;   // < 20224
    if (i < N_NODES) {
      cnt[i] = 0;
      deg[i] = 0.f;
      *(float4*)&Wgt[i * 4] = make_float4(0.f, 0.f, 0.f, 0.f);
    }
    if (i < JOUT) accum[i] = 0.f;
  }
}

// ---------------------------------------------------------------------------
// LSTM building blocks (L = literal local cg index 0..3).

#define INITACC(L, acc) do {                                                  \
  _Pragma("unroll") for (int g_ = 0; g_ < 4; ++g_) {                          \
    const float4 p0_ = *(const float4*)&bwRole[g_ * 128 + (L) * 16];          \
    const float4 p1_ = *(const float4*)&bwRole[g_ * 128 + (L) * 16 + 2];      \
    acc[g_][0] = p0_.x + xv * p0_.y;                                          \
    acc[g_][1] = p0_.z + xv * p0_.w;                                          \
    acc[g_][2] = p1_.x + xv * p1_.y;                                          \
    acc[g_][3] = p1_.z + xv * p1_.w;                                          \
  }                                                                           \
} while (0)

#define LDA(buf, L, KT) do {                                                  \
  _Pragma("unroll") for (int g_ = 0; g_ < 4; ++g_)                            \
    buf[g_] = *(const half8*)&WlRole[g_ * 16384 + (L) * 2048 + (KT) * 512];   \
} while (0)

#define MFA(acc, buf, KT) do {                                                \
  _Pragma("unroll") for (int g_ = 0; g_ < 4; ++g_)                            \
    acc[g_] = __builtin_amdgcn_mfma_f32_16x16x32_f16(                         \
        buf[g_], Bf[(KT)], acc[g_], 0, 0, 0);                                 \
} while (0)

#define PHASE4(L, acc) do {                                                   \
  const int cg_ = cgb + (L);                                                  \
  half4v hpack;                                                               \
  _Pragma("unroll") for (int r_ = 0; r_ < 4; ++r_) {                          \
    const float Be = __builtin_amdgcn_exp2f(-acc[0][r_]);                     \
    const float Ae = __builtin_amdgcn_exp2f(-acc[1][r_]);                     \
    const float De = __builtin_amdgcn_exp2f(acc[2][r_]);                      \
    const float Ee = __builtin_amdgcn_exp2f(-acc[3][r_]);                     \
    const float Ap = Ae + 1.f;                                                \
    const float Bp = Be + 1.f;                                                \
    const float Dp = De + 1.f;                                                \
    const float Nn = cst[(L) * 4 + r_] * Bp * Dp + Ap * (De - 1.f);           \
    const float cv = Nn * __builtin_amdgcn_rcpf(Ap * Bp * Dp);                \
    cst[(L) * 4 + r_] = cv;                                                   \
    const float cvc = fminf(fmaxf(cv, -10.f), 10.f);                          \
    const float Fe = __builtin_amdgcn_exp2f(K2E * cvc);                       \
    hpack[r_] = (_Float16)((Fe - 1.f) *                                       \
                __builtin_amdgcn_rcpf((Ee + 1.f) * (Fe + 1.f)));              \
  }                                                                           \
  const int lp_ = nl + 16 * (2 * (cg_ & 1) + wq_hi);                          \
  *(half4v*)&myscr[(cg_ >> 1) * 512 + lp_ * 8 + j0] = hpack;                  \
} while (0)

#define SB __builtin_amdgcn_sched_barrier(0)

// Pair-local sync: SIGNAL publishes epoch after a fence; WAITGE spins
// (lane 0) until the partner reaches the epoch, then fences.
#define SIGNAL(arr, val) do {                                                 \
  __threadfence_block();                                                      \
  if (ln == 0) arr[wv] = (val);                                               \
} while (0)
#define WAITGE(arr, val) do {                                                 \
  if (ln == 0) { while (arr[pw] < (val)) __builtin_amdgcn_s_sleep(1); }       \
  __builtin_amdgcn_wave_barrier();                                            \
  __threadfence_block();                                                      \
} while (0)

// One LSTM step (r27 form): wait partner's writes of step t-1, read Bf,
// SIGNAL flR IMMEDIATELY (earliest possible -- r28 proved delaying this
// serializes the pair), then depth-2 pipelined bodies.
#define LSTM_STEP(t) do {                                                     \
  WAITGE(flW, (t));                                                           \
  half8 Bf[4];                                                                \
  _Pragma("unroll") for (int kt_ = 0; kt_ < 4; ++kt_)                         \
    Bf[kt_] = *(const half8*)&scrLane[kt_ * 512];                             \
  SIGNAL(flR, (t) + 1);                                                       \
  floatx4 accA[4], accB[4];                                                   \
  half8 Aa[4], Ab[4];                                                         \
  /* body 0 */                                                                \
  INITACC(0, accA);                                                           \
  LDA(Aa, 0, 0); LDA(Ab, 0, 1);                                               \
  MFA(accA, Aa, 0); LDA(Aa, 0, 2);                                            \
  MFA(accA, Ab, 1); LDA(Ab, 0, 3);                                            \
  MFA(accA, Aa, 2); MFA(accA, Ab, 3);                                         \
  /* body 1 */                                                                \
  INITACC(1, accB); LDA(Aa, 1, 0); LDA(Ab, 1, 1);                             \
  WAITGE(flR, (t) + 1);                                                       \
  SB; PHASE4(0, accA);                                                        \
  MFA(accB, Aa, 0); LDA(Aa, 1, 2);                                            \
  MFA(accB, Ab, 1); LDA(Ab, 1, 3);                                            \
  MFA(accB, Aa, 2); MFA(accB, Ab, 3);                                         \
  /* body 2 */                                                                \
  INITACC(2, accA); LDA(Aa, 2, 0); LDA(Ab, 2, 1);                             \
  SB; PHASE4(1, accB);                                                        \
  MFA(accA, Aa, 0); LDA(Aa, 2, 2);                                            \
  MFA(accA, Ab, 1); LDA(Ab, 2, 3);                                            \
  MFA(accA, Aa, 2); MFA(accA, Ab, 3);                                         \
  /* body 3 */                                                                \
  INITACC(3, accB); LDA(Aa, 3, 0); LDA(Ab, 3, 1);                             \
  SB; PHASE4(2, accA);                                                        \
  MFA(accB, Aa, 0); LDA(Aa, 3, 2);                                            \
  MFA(accB, Ab, 1); LDA(Ab, 3, 3);                                            \
  MFA(accB, Aa, 2); MFA(accB, Ab, 3);                                         \
  PHASE4(3, accB);                                                            \
  SIGNAL(flW, (t) + 1);                                                       \
} while (0)

// ---------------------------------------------------------------------------
// Wave-pair LSTM + hidden bucket build. Blocks 0..NBLK-1: LSTM (10 waves,
// 5 groups x 16 nodes). Blocks NBLK..GRIDX-1: edge-bucket build + deg
// accumulation on the CUs the LSTM leaves idle.
__global__ __attribute__((amdgpu_flat_work_group_size(BTHR, BTHR),
                          amdgpu_waves_per_eu(3, 3)))
void lstm_stream_kernel(
    const float* __restrict__ xfeat, const _Float16* __restrict__ Wpack,
    const float* __restrict__ Wih, const float* __restrict__ bih,
    const float* __restrict__ bhh, _Float16* __restrict__ x1,
    const int* __restrict__ ei, const float* __restrict__ ew,
    int* __restrict__ cnt, int2* __restrict__ pairB, float* __restrict__ deg)
{
  const int tid  = threadIdx.x;   // 0..639

  if (blockIdx.x >= NBLK) {
    // ---- hidden edge-bucket build + deg on otherwise-idle CUs ----
    const int stride = (GRIDX - NBLK) * BTHR;
    for (int e = (blockIdx.x - NBLK) * BTHR + tid; e < N_EDGES; e += stride) {
      const int r = ei[e];
      const int c = ei[N_EDGES + e];
      const float w = ew[e];
      const int p = atomicAdd(&cnt[c], 1);
      pairB[(size_t)c * EDGE_CAP + p] = make_int2(r, __float_as_int(w));
      atomicAdd(&deg[c], w);
    }
    return;
  }

  extern __shared__ char dynlds[];
  _Float16* Wl  = (_Float16*)dynlds;                    // [128 tiles][64 lanes][8]
  float2*   bw  = (float2*)(dynlds + LDS_W);            // [512] (bias, wih) pre-scaled
  _Float16* scr = (_Float16*)(dynlds + LDS_W + LDS_BW); // [5][2048]
  volatile int* flR = (volatile int*)(dynlds + LDS_W + LDS_BW + LDS_SCR);
  volatile int* flW = flR + 16;

  const int wv   = tid >> 6;      // wave 0..9
  const int pw   = wv ^ 1;        // partner wave
  const int grp  = wv >> 1;       // node group 0..4
  const int role = wv & 1;        // 0: cg0-3, 1: cg4-7
  const int cgb  = role * 4;
  const int ln   = tid & 63;
  const int nl   = ln & 15;       // node within group
  const int quad = ln >> 4;
  const int n0   = blockIdx.x * NBB + grp * NBW;

  // stage packed Whh -> LDS (coalesced float4)
  {
    const float4* src = (const float4*)Wpack;
    float4* dst = (float4*)Wl;
    for (int i = tid; i < LDS_W / 16; i += BTHR) dst[i] = src[i];
  }
  for (int i = tid; i < 512; i += BTHR) {
    const float sc = ((i >> 7) == 2) ? K2E : L2E;
    bw[i] = make_float2((bih[i] + bhh[i]) * sc, Wih[i] * sc);
  }
  {
    float4* z = (float4*)scr;
    for (int i = tid; i < LDS_SCR / 16; i += BTHR)
      z[i] = make_float4(0.f, 0.f, 0.f, 0.f);
  }
  if (tid < 32) { flR[tid] = 0; }
  __syncthreads();   // staging barrier (the only block-wide one)

  _Float16* myscr = scr + grp * 2048;
  const _Float16* WlRole  = Wl + (size_t)cgb * 2048 + (size_t)ln * 8;
  const float2*   bwRole  = bw + cgb * 16 + quad * 4;
  const _Float16* scrLane = myscr + (size_t)ln * 8;
  const float* xrow = xfeat + (size_t)(n0 + nl) * T_STEPS;

  float cst[16];
  #pragma unroll
  for (int i = 0; i < 16; ++i) cst[i] = 0.f;

  const int wq_hi = quad >> 1;
  const int j0    = (quad & 1) * 4;

  float xv = xrow[0];

  #pragma unroll 1
  for (int t = 0; t < T_STEPS; ++t) {
    const float xn = xrow[(t + 1 <= 63) ? (t + 1) : 63];
    LSTM_STEP(t);
    xv = xn;
  }

  // epilogue: each role reads only its own written banks -> no final sync.
  #pragma unroll
  for (int k = 0; k < 2; ++k) {
    const int kt = role * 2 + k;
    half8 hf = *(const half8*)&scrLane[kt * 512];
    #pragma unroll
    for (int j = 0; j < 8; ++j)
      hf[j] = (_Float16)fmaxf((float)hf[j], 0.f);
    *(half8*)&x1[(size_t)(n0 + nl) * HDIM + kt * 32 + quad * 8] = hf;
  }
}

// ---------------------------------------------------------------------------
// FUSED middle: per block, 16 dest nodes. dinv computed on the fly from deg.
// A: bucket-aggregate x1 rows (4 dest/wave) -> z[16][132] fp16 LDS
// B: z @ gcnW^T + gcnb, relu -> zz (8 M-tiles over 4 waves)
// C: zz @ gatW^T -> xh global + att logits (12 M-tiles over 4 waves)
__global__ __launch_bounds__(256) void agg_gemm_att_kernel(
    const _Float16* __restrict__ x1, const float* __restrict__ deg,
    const int* __restrict__ cnt, const int2* __restrict__ pairB,
    const float* __restrict__ gcn_b,
    const _Float16* __restrict__ PG, const _Float16* __restrict__ PA,
    const float* __restrict__ att_src, const float* __restrict__ att_dst,
    _Float16* __restrict__ xh, float4* __restrict__ asrc,
    float4* __restrict__ adst)
{
  __shared__ float2 stg[4][64];
  __shared__ _Float16 z[16][132];
  __shared__ _Float16 zz[16][132];
  __shared__ float aS[JOUT], aD[JOUT];
  __shared__ float sAp[4][16][3], sDp[4][16][3];

  const int tid = threadIdx.x;
  const int ln = tid & 63;
  const int wv = tid >> 6;
  const int quad = ln >> 4;
  const int nl = ln & 15;
  const int nb = blockIdx.x * 16;

  for (int i = tid; i < JOUT; i += 256) { aS[i] = att_src[i]; aD[i] = att_dst[i]; }

  const half2v* x12 = (const half2v*)x1;
  // phase A: aggregate 4 dest nodes per wave (x1-space; GEMM linearity)
  #pragma unroll 1
  for (int d = 0; d < 4; ++d) {
    const int c = nb + wv * 4 + d;
    const float dc = rsqrtf(deg[c] + 1.0f);
    const half2v xc = x12[c * 64 + ln];
    float ax = (float)xc[0] * dc * dc, ay = (float)xc[1] * dc * dc; // self
    const int cc = cnt[c];
    const size_t base = (size_t)c * EDGE_CAP;
    for (int tb = 0; tb < cc; tb += 64) {
      const int ne = min(64, cc - tb);
      const int k = tb + ln;
      if (k < cc) {
        const int2 pr = pairB[base + k];
        stg[wv][ln] = make_float2(__int_as_float(pr.x),
            __int_as_float(pr.y) * rsqrtf(deg[pr.x] + 1.0f) * dc);
      }
      __builtin_amdgcn_wave_barrier();
      int i = 0;
      for (; i + 4 <= ne; i += 4) {
        float2 p0 = stg[wv][i],     p1 = stg[wv][i + 1];
        float2 p2 = stg[wv][i + 2], p3 = stg[wv][i + 3];
        const half2v a0 = x12[(size_t)__float_as_int(p0.x) * 64 + ln];
        const half2v a1 = x12[(size_t)__float_as_int(p1.x) * 64 + ln];
        const half2v a2 = x12[(size_t)__float_as_int(p2.x) * 64 + ln];
        const half2v a3 = x12[(size_t)__float_as_int(p3.x) * 64 + ln];
        ax += (float)a0[0] * p0.y + (float)a1[0] * p1.y +
              (float)a2[0] * p2.y + (float)a3[0] * p3.y;
        ay += (float)a0[1] * p0.y + (float)a1[1] * p1.y +
              (float)a2[1] * p2.y + (float)a3[1] * p3.y;
      }
      for (; i < ne; ++i) {
        float2 p0 = stg[wv][i];
        const half2v a0 = x12[(size_t)__float_as_int(p0.x) * 64 + ln];
        ax += (float)a0[0] * p0.y; ay += (float)a0[1] * p0.y;
      }
      __builtin_amdgcn_wave_barrier();
    }
    const int dn = wv * 4 + d;
    half2v o; o[0] = (_Float16)ax; o[1] = (_Float16)ay;
    *(half2v*)&z[dn][ln * 2] = o;
  }
  __syncthreads();

  // phase B: z @ gcnW^T -> relu+gcnb -> zz (wave wv: M-tiles 2wv, 2wv+1)
  {
    half8 Bf[4];
    #pragma unroll
    for (int kt = 0; kt < 4; ++kt)
      Bf[kt] = *(const half8*)&z[nl][kt * 32 + quad * 8];
    #pragma unroll
    for (int mm = 0; mm < 2; ++mm) {
      const int m = wv * 2 + mm;
      floatx4 acc = {0.f, 0.f, 0.f, 0.f};
      #pragma unroll
      for (int kt = 0; kt < 4; ++kt) {
        const half8 Af = *(const half8*)&PG[(size_t)((m * 4 + kt) * 64 + ln) * 8];
        acc = __builtin_amdgcn_mfma_f32_16x16x32_f16(Af, Bf[kt], acc, 0, 0, 0);
      }
      #pragma unroll
      for (int j = 0; j < 4; ++j) {
        const int jj = m * 16 + quad * 4 + j;
        zz[nl][jj] = (_Float16)fmaxf(acc[j] + gcn_b[jj], 0.f);
      }
    }
  }
  __syncthreads();

  // phase C: zz @ gatW^T -> xh + att partials (wave wv: M-tiles 3wv..3wv+2)
  {
    half8 Bf[4];
    #pragma unroll
    for (int kt = 0; kt < 4; ++kt)
      Bf[kt] = *(const half8*)&zz[nl][kt * 32 + quad * 8];
    float sA[3] = {0.f, 0.f, 0.f}, sD[3] = {0.f, 0.f, 0.f};
    #pragma unroll
    for (int mm = 0; mm < 3; ++mm) {
      const int m = wv * 3 + mm;
      floatx4 acc = {0.f, 0.f, 0.f, 0.f};
      #pragma unroll
      for (int kt = 0; kt < 4; ++kt) {
        const half8 Af = *(const half8*)&PA[(size_t)((m * 4 + kt) * 64 + ln) * 8];
        acc = __builtin_amdgcn_mfma_f32_16x16x32_f16(Af, Bf[kt], acc, 0, 0, 0);
      }
      const int h  = m >> 2;
      const int jo = (m & 3) * 16 + quad * 4;
      half4v o;
      #pragma unroll
      for (int j = 0; j < 4; ++j) {
        sA[h] += acc[j] * aS[h * 64 + jo + j];
        sD[h] += acc[j] * aD[h * 64 + jo + j];
        o[j] = (_Float16)acc[j];
      }
      *(half4v*)&xh[(size_t)(nb + nl) * JOUT + m * 16 + quad * 4] = o;
    }
    #pragma unroll
    for (int h = 0; h < 3; ++h) {
      sA[h] += __shfl_xor(sA[h], 16); sA[h] += __shfl_xor(sA[h], 32);
      sD[h] += __shfl_xor(sD[h], 16); sD[h] += __shfl_xor(sD[h], 32);
    }
    if (quad == 0) {
      #pragma unroll
      for (int h = 0; h < 3; ++h) {
        sAp[wv][nl][h] = sA[h];
        sDp[wv][nl][h] = sD[h];
      }
    }
  }
  __syncthreads();
  if (tid < 16) {
    float a0 = 0.f, a1 = 0.f, a2 = 0.f, d0 = 0.f, d1 = 0.f, d2 = 0.f;
    #pragma unroll
    for (int w = 0; w < 4; ++w) {
      a0 += sAp[w][tid][0]; a1 += sAp[w][tid][1]; a2 += sAp[w][tid][2];
      d0 += sDp[w][tid][0]; d1 += sDp[w][tid][1]; d2 += sDp[w][tid][2];
    }
    asrc[nb + tid] = make_float4(a0, a1, a2, 0.f);
    adst[nb + tid] = make_float4(d0, d1, d2, 0.f);
  }
}

// ---------------------------------------------------------------------------
// GAT softmax weights (mean-trick): one wave per destination c. Computes
// denom_c per head (single-pass, no max-sub; logits |.|<~4), then scatters
// alpha/denom into per-SOURCE weight sums W[s][h] (+ self term to W[c]).
__global__ __launch_bounds__(256) void gat_weight_kernel(
    const float4* __restrict__ asrc, const float4* __restrict__ adst,
    const int* __restrict__ cnt, const int2* __restrict__ pairB,
    float* __restrict__ W)
{
  const int lane = threadIdx.x & 63;
  const int wv = threadIdx.x >> 6;
  const int c = blockIdx.x * 4 + wv;
  const int cc = cnt[c];
  const size_t base = (size_t)c * EDGE_CAP;
  const float4 adc = adst[c];
  const float4 asc = asrc[c];
  const float se0 = __expf(lrelu(asc.x + adc.x));
  const float se1 = __expf(lrelu(asc.y + adc.y));
  const float se2 = __expf(lrelu(asc.z + adc.z));
  float dp0 = 0.f, dp1 = 0.f, dp2 = 0.f;
  float a0v[2], a1v[2], a2v[2]; int sv[2];
  #pragma unroll
  for (int it = 0; it < 2; ++it) {
    const int k = it * 64 + lane;
    sv[it] = -1;
    a0v[it] = 0.f; a1v[it] = 0.f; a2v[it] = 0.f;
    if (k < cc) {
      const int s = pairB[base + k].x;
      const float4 av = asrc[s];
      const float a0 = __expf(lrelu(av.x + adc.x));
      const float a1 = __expf(lrelu(av.y + adc.y));
      const float a2 = __expf(lrelu(av.z + adc.z));
      dp0 += a0; dp1 += a1; dp2 += a2;
      sv[it] = s; a0v[it] = a0; a1v[it] = a1; a2v[it] = a2;
    }
  }
  #pragma unroll
  for (int off = 1; off < 64; off <<= 1) {
    dp0 += __shfl_xor(dp0, off);
    dp1 += __shfl_xor(dp1, off);
    dp2 += __shfl_xor(dp2, off);
  }
  const float iv0 = 1.f / (dp0 + se0);
  const float iv1 = 1.f / (dp1 + se1);
  const float iv2 = 1.f / (dp2 + se2);
  if (lane == 0) {
    atomicAdd(&W[c * 4 + 0], se0 * iv0);
    atomicAdd(&W[c * 4 + 1], se1 * iv1);
    atomicAdd(&W[c * 4 + 2], se2 * iv2);
  }
  #pragma unroll
  for (int it = 0; it < 2; ++it) {
    if (sv[it] >= 0) {
      atomicAdd(&W[sv[it] * 4 + 0], a0v[it] * iv0);
      atomicAdd(&W[sv[it] * 4 + 1], a1v[it] * iv1);
      atomicAdd(&W[sv[it] * 4 + 2], a2v[it] * iv2);
    }
  }
}

// Final coalesced sweep: accum[j] += sum_s W[s][h] * xh[s][j].
__global__ __launch_bounds__(192) void gat_final_kernel(
    const _Float16* __restrict__ xh, const float* __restrict__ W,
    float* __restrict__ accum)
{
  const int j = threadIdx.x;          // 0..191
  const int h = j >> 6;
  float sum = 0.f;
  const int s0 = blockIdx.x * 80;
  for (int s = s0; s < s0 + 80; ++s)
    sum += W[s * 4 + h] * (float)xh[(size_t)s * JOUT + j];
  atomicAdd(&accum[j], sum);
}

__global__ void finalize_kernel(const float* __restrict__ accum,
                                const float* __restrict__ gat_b,
                                float* __restrict__ out)
{
  int j = threadIdx.x;
  if (j < JOUT) out[j] = accum[j] * (1.0f / N_NODES) + gat_b[j];
}

// ---------------------------------------------------------------------------
extern "C" void kernel_launch(void* const* d_in, const int* in_sizes, int n_in,
                              void* d_out, int out_size, void* d_ws, size_t ws_size,
                              hipStream_t stream)
{
  const float* xfeat = (const float*)d_in[0];
  const int*   eidx  = (const int*)d_in[1];
  const float* eattr = (const float*)d_in[2];
  const float* Wih   = (const float*)d_in[3];
  const float* Whh   = (const float*)d_in[4];
  const float* bihp  = (const float*)d_in[5];
  const float* bhhp  = (const float*)d_in[6];
  const float* gcnW  = (const float*)d_in[7];
  const float* gcnb  = (const float*)d_in[8];
  const float* gatW  = (const float*)d_in[9];
  const float* attS  = (const float*)d_in[10];
  const float* attD  = (const float*)d_in[11];
  const float* gatb  = (const float*)d_in[12];
  float* out = (float*)d_out;

  char* ws = (char*)d_ws;
  size_t off = 0;
  auto alloc = [&](size_t bytes) {
    char* p = ws + off;
    off += (bytes + 255) & ~size_t(255);
    return p;
  };
  _Float16*  x1     = (_Float16*)alloc((size_t)N_NODES * 128 * 2);
  _Float16*  xh     = (_Float16*)alloc((size_t)N_NODES * 192 * 2);
  float4*    asrc   = (float4*)alloc((size_t)N_NODES * 16);
  float4*    adst   = (float4*)alloc((size_t)N_NODES * 16);
  float*     deg    = (float*)alloc((size_t)N_NODES * 4);
  int*       cnt    = (int*)alloc((size_t)N_NODES * 4);
  int2*      pairB  = (int2*)alloc((size_t)N_NODES * EDGE_CAP * 8);
  float*     Wgt    = (float*)alloc((size_t)N_NODES * 4 * 4);
  float*     accum  = (float*)alloc(JOUT * 4);
  _Float16*  wpack  = (_Float16*)alloc(131072);
  _Float16*  wpackG = (_Float16*)alloc((size_t)128 * 128 * 2);
  _Float16*  wpackA = (_Float16*)alloc((size_t)192 * 128 * 2);

  // opt-in to >64KB dynamic LDS for the wave-pair LSTM (idempotent)
  hipFuncSetAttribute((const void*)lstm_stream_kernel,
                      hipFuncAttributeMaxDynamicSharedMemorySize, LDS_TOTAL);

  prep_kernel<<<131, 256, 0, stream>>>(Whh, wpack, gcnW, wpackG, gatW, wpackA,
                                       cnt, deg, Wgt, accum);
  // LSTM (blocks 0..249) + hidden edge-bucket+deg build (blocks 250..255)
  lstm_stream_kernel<<<GRIDX, BTHR, LDS_TOTAL, stream>>>(
      xfeat, wpack, Wih, bihp, bhhp, x1, eidx, eattr, cnt, pairB, deg);
  agg_gemm_att_kernel<<<N_NODES / 16, 256, 0, stream>>>(
      x1, deg, cnt, pairB, gcnb, wpackG, wpackA, attS, attD, xh, asrc, adst);
  gat_weight_kernel<<<N_NODES / 4, 256, 0, stream>>>(asrc, adst, cnt, pairB, Wgt);
  gat_final_kernel<<<N_NODES / 80, 192, 0, stream>>>(xh, Wgt, accum);
  finalize_kernel<<<1, 256, 0, stream>>>(accum, gatb, out);
}

// Round 16
// 556.572 us; speedup vs baseline: 1.3086x; 1.3024x over previous
//
#include <hip/hip_runtime.h>

// TemporalGAT: LSTM(T=64,H=128) -> ReLU -> GCNConv -> ReLU -> GATConv(3x64) -> mean
// Round 30: r29 post-mortem falsified the split-wait attribution. VALUBusy/
// MfmaUtil scaled exactly as 383/530 -> the LSTM blocks still run at 383us;
// the 640K contended global fp32 atomicAdd(deg) (added in r28, kept in r29)
// made the HIDDEN bucket-build blocks the dispatch's long pole (~530us).
// Fix (single change): LDS-privatized deg in the edge blocks -- they have
// 152KB of allocated-but-unused LDS; use 80KB as ldeg[20000], accumulate
// with fast LDS atomics during the scan, merge once with 20K coalesced
// global atomicAdds per block (120K total vs 640K contended). Hidden build
// returns under the 383us LSTM umbrella. Everything else unchanged from
// r29 (r27 LSTM_STEP, fused agg w/ on-the-fly rsqrt, 6 launches).

#define N_NODES 20000
#define T_STEPS 64
#define N_EDGES 640000
#define HDIM    128
#define JOUT    192   // HEADS*OUT = 3*64
#define NEG_SLOPE 0.2f
#define EDGE_CAP 128  // bucket slots per node (fixed input: max degree ~65)
#define NBW     16    // nodes per group
#define NGRP    5
#define NBB     (NBW * NGRP)   // 80 nodes per block
#define BTHR    640            // 10 waves: 5 groups x 2 roles
#define NBLK    250            // LSTM blocks; blocks NBLK..GRIDX-1 build buckets
#define GRIDX   256
#define LDS_W     131072                  // packed Whh fp16
#define LDS_BW    4096                    // (bias, wih) float2[512]
#define LDS_SCR   (NGRP * 4096)           // per-group h scratch
#define LDS_FLG   256                     // pair-sync flags (flR, flW)
#define LDS_TOTAL (LDS_W + LDS_BW + LDS_SCR + LDS_FLG)   // 155904

#define L2E  1.4426950408889634f
#define K2E  2.8853900817779268f   // 2*log2(e)

typedef _Float16 half8 __attribute__((ext_vector_type(8)));
typedef _Float16 half4v __attribute__((ext_vector_type(4)));
typedef _Float16 half2v __attribute__((ext_vector_type(2)));
typedef float floatx4 __attribute__((ext_vector_type(4)));

__device__ __forceinline__ float lrelu(float x) { return x > 0.f ? x : NEG_SLOPE * x; }

// ---------------------------------------------------------------------------
// prep: pack Whh (exp2-domain scaled), pack gcnW/gatW, zero cnt/deg/Wgt/accum.
__global__ __launch_bounds__(256) void prep_kernel(
    const float* __restrict__ Whh, _Float16* __restrict__ Wpack,
    const float* __restrict__ gcnW, _Float16* __restrict__ WpackG,
    const float* __restrict__ gatW, _Float16* __restrict__ WpackA,
    int* __restrict__ cnt, float* __restrict__ deg,
    float* __restrict__ Wgt, float* __restrict__ accum)
{
  const int b = blockIdx.x;
  const int tid = threadIdx.x;
  if (b < 32) {
    int i = b * 256 + tid;   // 0..8191
    int tile = i >> 6, lane = i & 63;
    int nt = tile >> 2, kt = tile & 3;
    int row = nt * 16 + (lane & 15);
    int c0  = kt * 32 + (lane >> 4) * 8;
    const float sc = ((row >> 7) == 2) ? K2E : L2E;
    half8 v;
    #pragma unroll
    for (int j = 0; j < 8; ++j)
      v[j] = (_Float16)(Whh[row * 128 + c0 + j] * sc);
    *(half8*)&Wpack[(size_t)i * 8] = v;
  } else if (b < 40) {
    int i = (b - 32) * 256 + tid;   // < 2048
    int tile = i >> 6, lane = i & 63;
    int mt = tile >> 2, kt = tile & 3;
    int row = mt * 16 + (lane & 15);
    int c0  = kt * 32 + (lane >> 4) * 8;
    half8 v;
    #pragma unroll
    for (int j = 0; j < 8; ++j) v[j] = (_Float16)gcnW[row * 128 + c0 + j];
    *(half8*)&WpackG[(size_t)i * 8] = v;
  } else if (b < 52) {
    int i = (b - 40) * 256 + tid;   // < 3072
    int tile = i >> 6, lane = i & 63;
    int mt = tile >> 2, kt = tile & 3;
    int row = mt * 16 + (lane & 15);
    int c0  = kt * 32 + (lane >> 4) * 8;
    half8 v;
    #pragma unroll
    for (int j = 0; j < 8; ++j) v[j] = (_Float16)gatW[row * 128 + c0 + j];
    *(half8*)&WpackA[(size_t)i * 8] = v;
  } else {
    int i = (b - 52) * 256 + tid;   // < 20224
    if (i < N_NODES) {
      cnt[i] = 0;
      deg[i] = 0.f;
      *(float4*)&Wgt[i * 4] = make_float4(0.f, 0.f, 0.f, 0.f);
    }
    if (i < JOUT) accum[i] = 0.f;
  }
}

// ---------------------------------------------------------------------------
// LSTM building blocks (L = literal local cg index 0..3).

#define INITACC(L, acc) do {                                                  \
  _Pragma("unroll") for (int g_ = 0; g_ < 4; ++g_) {                          \
    const float4 p0_ = *(const float4*)&bwRole[g_ * 128 + (L) * 16];          \
    const float4 p1_ = *(const float4*)&bwRole[g_ * 128 + (L) * 16 + 2];      \
    acc[g_][0] = p0_.x + xv * p0_.y;                                          \
    acc[g_][1] = p0_.z + xv * p0_.w;                                          \
    acc[g_][2] = p1_.x + xv * p1_.y;                                          \
    acc[g_][3] = p1_.z + xv * p1_.w;                                          \
  }                                                                           \
} while (0)

#define LDA(buf, L, KT) do {                                                  \
  _Pragma("unroll") for (int g_ = 0; g_ < 4; ++g_)                            \
    buf[g_] = *(const half8*)&WlRole[g_ * 16384 + (L) * 2048 + (KT) * 512];   \
} while (0)

#define MFA(acc, buf, KT) do {                                                \
  _Pragma("unroll") for (int g_ = 0; g_ < 4; ++g_)                            \
    acc[g_] = __builtin_amdgcn_mfma_f32_16x16x32_f16(                         \
        buf[g_], Bf[(KT)], acc[g_], 0, 0, 0);                                 \
} while (0)

#define PHASE4(L, acc) do {                                                   \
  const int cg_ = cgb + (L);                                                  \
  half4v hpack;                                                               \
  _Pragma("unroll") for (int r_ = 0; r_ < 4; ++r_) {                          \
    const float Be = __builtin_amdgcn_exp2f(-acc[0][r_]);                     \
    const float Ae = __builtin_amdgcn_exp2f(-acc[1][r_]);                     \
    const float De = __builtin_amdgcn_exp2f(acc[2][r_]);                      \
    const float Ee = __builtin_amdgcn_exp2f(-acc[3][r_]);                     \
    const float Ap = Ae + 1.f;                                                \
    const float Bp = Be + 1.f;                                                \
    const float Dp = De + 1.f;                                                \
    const float Nn = cst[(L) * 4 + r_] * Bp * Dp + Ap * (De - 1.f);           \
    const float cv = Nn * __builtin_amdgcn_rcpf(Ap * Bp * Dp);                \
    cst[(L) * 4 + r_] = cv;                                                   \
    const float cvc = fminf(fmaxf(cv, -10.f), 10.f);                          \
    const float Fe = __builtin_amdgcn_exp2f(K2E * cvc);                       \
    hpack[r_] = (_Float16)((Fe - 1.f) *                                       \
                __builtin_amdgcn_rcpf((Ee + 1.f) * (Fe + 1.f)));              \
  }                                                                           \
  const int lp_ = nl + 16 * (2 * (cg_ & 1) + wq_hi);                          \
  *(half4v*)&myscr[(cg_ >> 1) * 512 + lp_ * 8 + j0] = hpack;                  \
} while (0)

#define SB __builtin_amdgcn_sched_barrier(0)

// Pair-local sync: SIGNAL publishes epoch after a fence; WAITGE spins
// (lane 0) until the partner reaches the epoch, then fences.
#define SIGNAL(arr, val) do {                                                 \
  __threadfence_block();                                                      \
  if (ln == 0) arr[wv] = (val);                                               \
} while (0)
#define WAITGE(arr, val) do {                                                 \
  if (ln == 0) { while (arr[pw] < (val)) __builtin_amdgcn_s_sleep(1); }       \
  __builtin_amdgcn_wave_barrier();                                            \
  __threadfence_block();                                                      \
} while (0)

// One LSTM step (r27 form): wait partner's writes of step t-1, read Bf,
// SIGNAL flR IMMEDIATELY, then depth-2 pipelined bodies.
#define LSTM_STEP(t) do {                                                     \
  WAITGE(flW, (t));                                                           \
  half8 Bf[4];                                                                \
  _Pragma("unroll") for (int kt_ = 0; kt_ < 4; ++kt_)                         \
    Bf[kt_] = *(const half8*)&scrLane[kt_ * 512];                             \
  SIGNAL(flR, (t) + 1);                                                       \
  floatx4 accA[4], accB[4];                                                   \
  half8 Aa[4], Ab[4];                                                         \
  /* body 0 */                                                                \
  INITACC(0, accA);                                                           \
  LDA(Aa, 0, 0); LDA(Ab, 0, 1);                                               \
  MFA(accA, Aa, 0); LDA(Aa, 0, 2);                                            \
  MFA(accA, Ab, 1); LDA(Ab, 0, 3);                                            \
  MFA(accA, Aa, 2); MFA(accA, Ab, 3);                                         \
  /* body 1 */                                                                \
  INITACC(1, accB); LDA(Aa, 1, 0); LDA(Ab, 1, 1);                             \
  WAITGE(flR, (t) + 1);                                                       \
  SB; PHASE4(0, accA);                                                        \
  MFA(accB, Aa, 0); LDA(Aa, 1, 2);                                            \
  MFA(accB, Ab, 1); LDA(Ab, 1, 3);                                            \
  MFA(accB, Aa, 2); MFA(accB, Ab, 3);                                         \
  /* body 2 */                                                                \
  INITACC(2, accA); LDA(Aa, 2, 0); LDA(Ab, 2, 1);                             \
  SB; PHASE4(1, accB);                                                        \
  MFA(accA, Aa, 0); LDA(Aa, 2, 2);                                            \
  MFA(accA, Ab, 1); LDA(Ab, 2, 3);                                            \
  MFA(accA, Aa, 2); MFA(accA, Ab, 3);                                         \
  /* body 3 */                                                                \
  INITACC(3, accB); LDA(Aa, 3, 0); LDA(Ab, 3, 1);                             \
  SB; PHASE4(2, accA);                                                        \
  MFA(accB, Aa, 0); LDA(Aa, 3, 2);                                            \
  MFA(accB, Ab, 1); LDA(Ab, 3, 3);                                            \
  MFA(accB, Aa, 2); MFA(accB, Ab, 3);                                         \
  PHASE4(3, accB);                                                            \
  SIGNAL(flW, (t) + 1);                                                       \
} while (0)

// ---------------------------------------------------------------------------
// Wave-pair LSTM + hidden bucket build. Blocks 0..NBLK-1: LSTM (10 waves,
// 5 groups x 16 nodes). Blocks NBLK..GRIDX-1: edge-bucket build + deg via
// LDS-PRIVATIZED accumulation (80KB ldeg in the otherwise-unused LDS),
// merged once with 20K coalesced global atomics per block.
__global__ __attribute__((amdgpu_flat_work_group_size(BTHR, BTHR),
                          amdgpu_waves_per_eu(3, 3)))
void lstm_stream_kernel(
    const float* __restrict__ xfeat, const _Float16* __restrict__ Wpack,
    const float* __restrict__ Wih, const float* __restrict__ bih,
    const float* __restrict__ bhh, _Float16* __restrict__ x1,
    const int* __restrict__ ei, const float* __restrict__ ew,
    int* __restrict__ cnt, int2* __restrict__ pairB, float* __restrict__ deg)
{
  extern __shared__ char dynlds[];
  const int tid  = threadIdx.x;   // 0..639

  if (blockIdx.x >= NBLK) {
    // ---- hidden edge-bucket build + LDS-privatized deg ----
    float* ldeg = (float*)dynlds;   // 20000 floats = 80KB (< LDS_TOTAL)
    for (int i = tid; i < N_NODES; i += BTHR) ldeg[i] = 0.f;
    __syncthreads();
    const int stride = (GRIDX - NBLK) * BTHR;
    for (int e = (blockIdx.x - NBLK) * BTHR + tid; e < N_EDGES; e += stride) {
      const int r = ei[e];
      const int c = ei[N_EDGES + e];
      const float w = ew[e];
      const int p = atomicAdd(&cnt[c], 1);
      pairB[(size_t)c * EDGE_CAP + p] = make_int2(r, __float_as_int(w));
      atomicAdd(&ldeg[c], w);   // LDS atomic: fast, block-private
    }
    __syncthreads();
    for (int i = tid; i < N_NODES; i += BTHR) {
      const float v = ldeg[i];
      if (v != 0.f) atomicAdd(&deg[i], v);
    }
    return;
  }

  _Float16* Wl  = (_Float16*)dynlds;                    // [128 tiles][64 lanes][8]
  float2*   bw  = (float2*)(dynlds + LDS_W);            // [512] (bias, wih) pre-scaled
  _Float16* scr = (_Float16*)(dynlds + LDS_W + LDS_BW); // [5][2048]
  volatile int* flR = (volatile int*)(dynlds + LDS_W + LDS_BW + LDS_SCR);
  volatile int* flW = flR + 16;

  const int wv   = tid >> 6;      // wave 0..9
  const int pw   = wv ^ 1;        // partner wave
  const int grp  = wv >> 1;       // node group 0..4
  const int role = wv & 1;        // 0: cg0-3, 1: cg4-7
  const int cgb  = role * 4;
  const int ln   = tid & 63;
  const int nl   = ln & 15;       // node within group
  const int quad = ln >> 4;
  const int n0   = blockIdx.x * NBB + grp * NBW;

  // stage packed Whh -> LDS (coalesced float4)
  {
    const float4* src = (const float4*)Wpack;
    float4* dst = (float4*)Wl;
    for (int i = tid; i < LDS_W / 16; i += BTHR) dst[i] = src[i];
  }
  for (int i = tid; i < 512; i += BTHR) {
    const float sc = ((i >> 7) == 2) ? K2E : L2E;
    bw[i] = make_float2((bih[i] + bhh[i]) * sc, Wih[i] * sc);
  }
  {
    float4* z = (float4*)scr;
    for (int i = tid; i < LDS_SCR / 16; i += BTHR)
      z[i] = make_float4(0.f, 0.f, 0.f, 0.f);
  }
  if (tid < 32) { flR[tid] = 0; }
  __syncthreads();   // staging barrier (the only block-wide one)

  _Float16* myscr = scr + grp * 2048;
  const _Float16* WlRole  = Wl + (size_t)cgb * 2048 + (size_t)ln * 8;
  const float2*   bwRole  = bw + cgb * 16 + quad * 4;
  const _Float16* scrLane = myscr + (size_t)ln * 8;
  const float* xrow = xfeat + (size_t)(n0 + nl) * T_STEPS;

  float cst[16];
  #pragma unroll
  for (int i = 0; i < 16; ++i) cst[i] = 0.f;

  const int wq_hi = quad >> 1;
  const int j0    = (quad & 1) * 4;

  float xv = xrow[0];

  #pragma unroll 1
  for (int t = 0; t < T_STEPS; ++t) {
    const float xn = xrow[(t + 1 <= 63) ? (t + 1) : 63];
    LSTM_STEP(t);
    xv = xn;
  }

  // epilogue: each role reads only its own written banks -> no final sync.
  #pragma unroll
  for (int k = 0; k < 2; ++k) {
    const int kt = role * 2 + k;
    half8 hf = *(const half8*)&scrLane[kt * 512];
    #pragma unroll
    for (int j = 0; j < 8; ++j)
      hf[j] = (_Float16)fmaxf((float)hf[j], 0.f);
    *(half8*)&x1[(size_t)(n0 + nl) * HDIM + kt * 32 + quad * 8] = hf;
  }
}

// ---------------------------------------------------------------------------
// FUSED middle: per block, 16 dest nodes. dinv computed on the fly from deg.
// A: bucket-aggregate x1 rows (4 dest/wave) -> z[16][132] fp16 LDS
// B: z @ gcnW^T + gcnb, relu -> zz (8 M-tiles over 4 waves)
// C: zz @ gatW^T -> xh global + att logits (12 M-tiles over 4 waves)
__global__ __launch_bounds__(256) void agg_gemm_att_kernel(
    const _Float16* __restrict__ x1, const float* __restrict__ deg,
    const int* __restrict__ cnt, const int2* __restrict__ pairB,
    const float* __restrict__ gcn_b,
    const _Float16* __restrict__ PG, const _Float16* __restrict__ PA,
    const float* __restrict__ att_src, const float* __restrict__ att_dst,
    _Float16* __restrict__ xh, float4* __restrict__ asrc,
    float4* __restrict__ adst)
{
  __shared__ float2 stg[4][64];
  __shared__ _Float16 z[16][132];
  __shared__ _Float16 zz[16][132];
  __shared__ float aS[JOUT], aD[JOUT];
  __shared__ float sAp[4][16][3], sDp[4][16][3];

  const int tid = threadIdx.x;
  const int ln = tid & 63;
  const int wv = tid >> 6;
  const int quad = ln >> 4;
  const int nl = ln & 15;
  const int nb = blockIdx.x * 16;

  for (int i = tid; i < JOUT; i += 256) { aS[i] = att_src[i]; aD[i] = att_dst[i]; }

  const half2v* x12 = (const half2v*)x1;
  // phase A: aggregate 4 dest nodes per wave (x1-space; GEMM linearity)
  #pragma unroll 1
  for (int d = 0; d < 4; ++d) {
    const int c = nb + wv * 4 + d;
    const float dc = rsqrtf(deg[c] + 1.0f);
    const half2v xc = x12[c * 64 + ln];
    float ax = (float)xc[0] * dc * dc, ay = (float)xc[1] * dc * dc; // self
    const int cc = cnt[c];
    const size_t base = (size_t)c * EDGE_CAP;
    for (int tb = 0; tb < cc; tb += 64) {
      const int ne = min(64, cc - tb);
      const int k = tb + ln;
      if (k < cc) {
        const int2 pr = pairB[base + k];
        stg[wv][ln] = make_float2(__int_as_float(pr.x),
            __int_as_float(pr.y) * rsqrtf(deg[pr.x] + 1.0f) * dc);
      }
      __builtin_amdgcn_wave_barrier();
      int i = 0;
      for (; i + 4 <= ne; i += 4) {
        float2 p0 = stg[wv][i],     p1 = stg[wv][i + 1];
        float2 p2 = stg[wv][i + 2], p3 = stg[wv][i + 3];
        const half2v a0 = x12[(size_t)__float_as_int(p0.x) * 64 + ln];
        const half2v a1 = x12[(size_t)__float_as_int(p1.x) * 64 + ln];
        const half2v a2 = x12[(size_t)__float_as_int(p2.x) * 64 + ln];
        const half2v a3 = x12[(size_t)__float_as_int(p3.x) * 64 + ln];
        ax += (float)a0[0] * p0.y + (float)a1[0] * p1.y +
              (float)a2[0] * p2.y + (float)a3[0] * p3.y;
        ay += (float)a0[1] * p0.y + (float)a1[1] * p1.y +
              (float)a2[1] * p2.y + (float)a3[1] * p3.y;
      }
      for (; i < ne; ++i) {
        float2 p0 = stg[wv][i];
        const half2v a0 = x12[(size_t)__float_as_int(p0.x) * 64 + ln];
        ax += (float)a0[0] * p0.y; ay += (float)a0[1] * p0.y;
      }
      __builtin_amdgcn_wave_barrier();
    }
    const int dn = wv * 4 + d;
    half2v o; o[0] = (_Float16)ax; o[1] = (_Float16)ay;
    *(half2v*)&z[dn][ln * 2] = o;
  }
  __syncthreads();

  // phase B: z @ gcnW^T -> relu+gcnb -> zz (wave wv: M-tiles 2wv, 2wv+1)
  {
    half8 Bf[4];
    #pragma unroll
    for (int kt = 0; kt < 4; ++kt)
      Bf[kt] = *(const half8*)&z[nl][kt * 32 + quad * 8];
    #pragma unroll
    for (int mm = 0; mm < 2; ++mm) {
      const int m = wv * 2 + mm;
      floatx4 acc = {0.f, 0.f, 0.f, 0.f};
      #pragma unroll
      for (int kt = 0; kt < 4; ++kt) {
        const half8 Af = *(const half8*)&PG[(size_t)((m * 4 + kt) * 64 + ln) * 8];
        acc = __builtin_amdgcn_mfma_f32_16x16x32_f16(Af, Bf[kt], acc, 0, 0, 0);
      }
      #pragma unroll
      for (int j = 0; j < 4; ++j) {
        const int jj = m * 16 + quad * 4 + j;
        zz[nl][jj] = (_Float16)fmaxf(acc[j] + gcn_b[jj], 0.f);
      }
    }
  }
  __syncthreads();

  // phase C: zz @ gatW^T -> xh + att partials (wave wv: M-tiles 3wv..3wv+2)
  {
    half8 Bf[4];
    #pragma unroll
    for (int kt = 0; kt < 4; ++kt)
      Bf[kt] = *(const half8*)&zz[nl][kt * 32 + quad * 8];
    float sA[3] = {0.f, 0.f, 0.f}, sD[3] = {0.f, 0.f, 0.f};
    #pragma unroll
    for (int mm = 0; mm < 3; ++mm) {
      const int m = wv * 3 + mm;
      floatx4 acc = {0.f, 0.f, 0.f, 0.f};
      #pragma unroll
      for (int kt = 0; kt < 4; ++kt) {
        const half8 Af = *(const half8*)&PA[(size_t)((m * 4 + kt) * 64 + ln) * 8];
        acc = __builtin_amdgcn_mfma_f32_16x16x32_f16(Af, Bf[kt], acc, 0, 0, 0);
      }
      const int h  = m >> 2;
      const int jo = (m & 3) * 16 + quad * 4;
      half4v o;
      #pragma unroll
      for (int j = 0; j < 4; ++j) {
        sA[h] += acc[j] * aS[h * 64 + jo + j];
        sD[h] += acc[j] * aD[h * 64 + jo + j];
        o[j] = (_Float16)acc[j];
      }
      *(half4v*)&xh[(size_t)(nb + nl) * JOUT + m * 16 + quad * 4] = o;
    }
    #pragma unroll
    for (int h = 0; h < 3; ++h) {
      sA[h] += __shfl_xor(sA[h], 16); sA[h] += __shfl_xor(sA[h], 32);
      sD[h] += __shfl_xor(sD[h], 16); sD[h] += __shfl_xor(sD[h], 32);
    }
    if (quad == 0) {
      #pragma unroll
      for (int h = 0; h < 3; ++h) {
        sAp[wv][nl][h] = sA[h];
        sDp[wv][nl][h] = sD[h];
      }
    }
  }
  __syncthreads();
  if (tid < 16) {
    float a0 = 0.f, a1 = 0.f, a2 = 0.f, d0 = 0.f, d1 = 0.f, d2 = 0.f;
    #pragma unroll
    for (int w = 0; w < 4; ++w) {
      a0 += sAp[w][tid][0]; a1 += sAp[w][tid][1]; a2 += sAp[w][tid][2];
      d0 += sDp[w][tid][0]; d1 += sDp[w][tid][1]; d2 += sDp[w][tid][2];
    }
    asrc[nb + tid] = make_float4(a0, a1, a2, 0.f);
    adst[nb + tid] = make_float4(d0, d1, d2, 0.f);
  }
}

// ---------------------------------------------------------------------------
// GAT softmax weights (mean-trick): one wave per destination c. Computes
// denom_c per head (single-pass, no max-sub; logits |.|<~4), then scatters
// alpha/denom into per-SOURCE weight sums W[s][h] (+ self term to W[c]).
__global__ __launch_bounds__(256) void gat_weight_kernel(
    const float4* __restrict__ asrc, const float4* __restrict__ adst,
    const int* __restrict__ cnt, const int2* __restrict__ pairB,
    float* __restrict__ W)
{
  const int lane = threadIdx.x & 63;
  const int wv = threadIdx.x >> 6;
  const int c = blockIdx.x * 4 + wv;
  const int cc = cnt[c];
  const size_t base = (size_t)c * EDGE_CAP;
  const float4 adc = adst[c];
  const float4 asc = asrc[c];
  const float se0 = __expf(lrelu(asc.x + adc.x));
  const float se1 = __expf(lrelu(asc.y + adc.y));
  const float se2 = __expf(lrelu(asc.z + adc.z));
  float dp0 = 0.f, dp1 = 0.f, dp2 = 0.f;
  float a0v[2], a1v[2], a2v[2]; int sv[2];
  #pragma unroll
  for (int it = 0; it < 2; ++it) {
    const int k = it * 64 + lane;
    sv[it] = -1;
    a0v[it] = 0.f; a1v[it] = 0.f; a2v[it] = 0.f;
    if (k < cc) {
      const int s = pairB[base + k].x;
      const float4 av = asrc[s];
      const float a0 = __expf(lrelu(av.x + adc.x));
      const float a1 = __expf(lrelu(av.y + adc.y));
      const float a2 = __expf(lrelu(av.z + adc.z));
      dp0 += a0; dp1 += a1; dp2 += a2;
      sv[it] = s; a0v[it] = a0; a1v[it] = a1; a2v[it] = a2;
    }
  }
  #pragma unroll
  for (int off = 1; off < 64; off <<= 1) {
    dp0 += __shfl_xor(dp0, off);
    dp1 += __shfl_xor(dp1, off);
    dp2 += __shfl_xor(dp2, off);
  }
  const float iv0 = 1.f / (dp0 + se0);
  const float iv1 = 1.f / (dp1 + se1);
  const float iv2 = 1.f / (dp2 + se2);
  if (lane == 0) {
    atomicAdd(&W[c * 4 + 0], se0 * iv0);
    atomicAdd(&W[c * 4 + 1], se1 * iv1);
    atomicAdd(&W[c * 4 + 2], se2 * iv2);
  }
  #pragma unroll
  for (int it = 0; it < 2; ++it) {
    if (sv[it] >= 0) {
      atomicAdd(&W[sv[it] * 4 + 0], a0v[it] * iv0);
      atomicAdd(&W[sv[it] * 4 + 1], a1v[it] * iv1);
      atomicAdd(&W[sv[it] * 4 + 2], a2v[it] * iv2);
    }
  }
}

// Final coalesced sweep: accum[j] += sum_s W[s][h] * xh[s][j].
__global__ __launch_bounds__(192) void gat_final_kernel(
    const _Float16* __restrict__ xh, const float* __restrict__ W,
    float* __restrict__ accum)
{
  const int j = threadIdx.x;          // 0..191
  const int h = j >> 6;
  float sum = 0.f;
  const int s0 = blockIdx.x * 80;
  for (int s = s0; s < s0 + 80; ++s)
    sum += W[s * 4 + h] * (float)xh[(size_t)s * JOUT + j];
  atomicAdd(&accum[j], sum);
}

__global__ void finalize_kernel(const float* __restrict__ accum,
                                const float* __restrict__ gat_b,
                                float* __restrict__ out)
{
  int j = threadIdx.x;
  if (j < JOUT) out[j] = accum[j] * (1.0f / N_NODES) + gat_b[j];
}

// ---------------------------------------------------------------------------
extern "C" void kernel_launch(void* const* d_in, const int* in_sizes, int n_in,
                              void* d_out, int out_size, void* d_ws, size_t ws_size,
                              hipStream_t stream)
{
  const float* xfeat = (const float*)d_in[0];
  const int*   eidx  = (const int*)d_in[1];
  const float* eattr = (const float*)d_in[2];
  const float* Wih   = (const float*)d_in[3];
  const float* Whh   = (const float*)d_in[4];
  const float* bihp  = (const float*)d_in[5];
  const float* bhhp  = (const float*)d_in[6];
  const float* gcnW  = (const float*)d_in[7];
  const float* gcnb  = (const float*)d_in[8];
  const float* gatW  = (const float*)d_in[9];
  const float* attS  = (const float*)d_in[10];
  const float* attD  = (const float*)d_in[11];
  const float* gatb  = (const float*)d_in[12];
  float* out = (float*)d_out;

  char* ws = (char*)d_ws;
  size_t off = 0;
  auto alloc = [&](size_t bytes) {
    char* p = ws + off;
    off += (bytes + 255) & ~size_t(255);
    return p;
  };
  _Float16*  x1     = (_Float16*)alloc((size_t)N_NODES * 128 * 2);
  _Float16*  xh     = (_Float16*)alloc((size_t)N_NODES * 192 * 2);
  float4*    asrc   = (float4*)alloc((size_t)N_NODES * 16);
  float4*    adst   = (float4*)alloc((size_t)N_NODES * 16);
  float*     deg    = (float*)alloc((size_t)N_NODES * 4);
  int*       cnt    = (int*)alloc((size_t)N_NODES * 4);
  int2*      pairB  = (int2*)alloc((size_t)N_NODES * EDGE_CAP * 8);
  float*     Wgt    = (float*)alloc((size_t)N_NODES * 4 * 4);
  float*     accum  = (float*)alloc(JOUT * 4);
  _Float16*  wpack  = (_Float16*)alloc(131072);
  _Float16*  wpackG = (_Float16*)alloc((size_t)128 * 128 * 2);
  _Float16*  wpackA = (_Float16*)alloc((size_t)192 * 128 * 2);

  // opt-in to >64KB dynamic LDS for the wave-pair LSTM (idempotent)
  hipFuncSetAttribute((const void*)lstm_stream_kernel,
                      hipFuncAttributeMaxDynamicSharedMemorySize, LDS_TOTAL);

  prep_kernel<<<131, 256, 0, stream>>>(Whh, wpack, gcnW, wpackG, gatW, wpackA,
                                       cnt, deg, Wgt, accum);
  // LSTM (blocks 0..249) + hidden edge-bucket+deg build (blocks 250..255)
  lstm_stream_kernel<<<GRIDX, BTHR, LDS_TOTAL, stream>>>(
      xfeat, wpack, Wih, bihp, bhhp, x1, eidx, eattr, cnt, pairB, deg);
  agg_gemm_att_kernel<<<N_NODES / 16, 256, 0, stream>>>(
      x1, deg, cnt, pairB, gcnb, wpackG, wpackA, attS, attD, xh, asrc, adst);
  gat_weight_kernel<<<N_NODES / 4, 256, 0, stream>>>(asrc, adst, cnt, pairB, Wgt);
  gat_final_kernel<<<N_NODES / 80, 192, 0, stream>>>(xh, Wgt, accum);
  finalize_kernel<<<1, 256, 0, stream>>>(accum, gatb, out);
}

// Round 17
// 553.941 us; speedup vs baseline: 1.3148x; 1.0048x over previous
//
#include <hip/hip_runtime.h>

// TemporalGAT: LSTM(T=64,H=128) -> ReLU -> GCNConv -> ReLU -> GATConv(3x64) -> mean
// Round 31: LSTM occupancy 2.5 -> 3 waves/SIMD by packing SIX 16-node
// groups per block (was 5). LDS = 128K Whh + 4K bw + 6x4K scr + flags =
// 160000B <= 163840 (fits the 160KiB CU limit). Block = 768 thr = 12
// waves; kernel is latency-bound (VALUBusy 51%, ~49% dependency stall),
// so +20% resident waves should convert ~linearly (same mechanism as
// r18's occupancy win). Grid: 209 LSTM blocks (208 full + 1 partial with
// clamped reads / guarded writes) + 6 hidden edge-builder blocks = 215.
// SINGLE change vs r30 for clean attribution (r28/r29 lesson).

#define N_NODES 20000
#define T_STEPS 64
#define N_EDGES 640000
#define HDIM    128
#define JOUT    192   // HEADS*OUT = 3*64
#define NEG_SLOPE 0.2f
#define EDGE_CAP 128  // bucket slots per node (fixed input: max degree ~65)
#define NBW     16    // nodes per group
#define NGRP    6
#define NBB     (NBW * NGRP)   // 96 nodes per block
#define BTHR    768            // 12 waves: 6 groups x 2 roles
#define NBLK    209            // ceil(20000/96) LSTM blocks
#define GRIDX   215            // + 6 hidden edge-builder blocks
#define LDS_W     131072                  // packed Whh fp16
#define LDS_BW    4096                    // (bias, wih) float2[512]
#define LDS_SCR   (NGRP * 4096)           // per-group h scratch (24576)
#define LDS_FLG   256                     // pair-sync flags (flR, flW)
#define LDS_TOTAL (LDS_W + LDS_BW + LDS_SCR + LDS_FLG)   // 160000

#define L2E  1.4426950408889634f
#define K2E  2.8853900817779268f   // 2*log2(e)

typedef _Float16 half8 __attribute__((ext_vector_type(8)));
typedef _Float16 half4v __attribute__((ext_vector_type(4)));
typedef _Float16 half2v __attribute__((ext_vector_type(2)));
typedef float floatx4 __attribute__((ext_vector_type(4)));

__device__ __forceinline__ float lrelu(float x) { return x > 0.f ? x : NEG_SLOPE * x; }

// ---------------------------------------------------------------------------
// prep: pack Whh (exp2-domain scaled), pack gcnW/gatW, zero cnt/deg/Wgt/accum.
__global__ __launch_bounds__(256) void prep_kernel(
    const float* __restrict__ Whh, _Float16* __restrict__ Wpack,
    const float* __restrict__ gcnW, _Float16* __restrict__ WpackG,
    const float* __restrict__ gatW, _Float16* __restrict__ WpackA,
    int* __restrict__ cnt, float* __restrict__ deg,
    float* __restrict__ Wgt, float* __restrict__ accum)
{
  const int b = blockIdx.x;
  const int tid = threadIdx.x;
  if (b < 32) {
    int i = b * 256 + tid;   // 0..8191
    int tile = i >> 6, lane = i & 63;
    int nt = tile >> 2, kt = tile & 3;
    int row = nt * 16 + (lane & 15);
    int c0  = kt * 32 + (lane >> 4) * 8;
    const float sc = ((row >> 7) == 2) ? K2E : L2E;
    half8 v;
    #pragma unroll
    for (int j = 0; j < 8; ++j)
      v[j] = (_Float16)(Whh[row * 128 + c0 + j] * sc);
    *(half8*)&Wpack[(size_t)i * 8] = v;
  } else if (b < 40) {
    int i = (b - 32) * 256 + tid;   // < 2048
    int tile = i >> 6, lane = i & 63;
    int mt = tile >> 2, kt = tile & 3;
    int row = mt * 16 + (lane & 15);
    int c0  = kt * 32 + (lane >> 4) * 8;
    half8 v;
    #pragma unroll
    for (int j = 0; j < 8; ++j) v[j] = (_Float16)gcnW[row * 128 + c0 + j];
    *(half8*)&WpackG[(size_t)i * 8] = v;
  } else if (b < 52) {
    int i = (b - 40) * 256 + tid;   // < 3072
    int tile = i >> 6, lane = i & 63;
    int mt = tile >> 2, kt = tile & 3;
    int row = mt * 16 + (lane & 15);
    int c0  = kt * 32 + (lane >> 4) * 8;
    half8 v;
    #pragma unroll
    for (int j = 0; j < 8; ++j) v[j] = (_Float16)gatW[row * 128 + c0 + j];
    *(half8*)&WpackA[(size_t)i * 8] = v;
  } else {
    int i = (b - 52) * 256 + tid;   // < 20224
    if (i < N_NODES) {
      cnt[i] = 0;
      deg[i] = 0.f;
      *(float4*)&Wgt[i * 4] = make_float4(0.f, 0.f, 0.f, 0.f);
    }
    if (i < JOUT) accum[i] = 0.f;
  }
}

// ---------------------------------------------------------------------------
// LSTM building blocks (L = literal local cg index 0..3).

#define INITACC(L, acc) do {                                                  \
  _Pragma("unroll") for (int g_ = 0; g_ < 4; ++g_) {                          \
    const float4 p0_ = *(const float4*)&bwRole[g_ * 128 + (L) * 16];          \
    const float4 p1_ = *(const float4*)&bwRole[g_ * 128 + (L) * 16 + 2];      \
    acc[g_][0] = p0_.x + xv * p0_.y;                                          \
    acc[g_][1] = p0_.z + xv * p0_.w;                                          \
    acc[g_][2] = p1_.x + xv * p1_.y;                                          \
    acc[g_][3] = p1_.z + xv * p1_.w;                                          \
  }                                                                           \
} while (0)

#define LDA(buf, L, KT) do {                                                  \
  _Pragma("unroll") for (int g_ = 0; g_ < 4; ++g_)                            \
    buf[g_] = *(const half8*)&WlRole[g_ * 16384 + (L) * 2048 + (KT) * 512];   \
} while (0)

#define MFA(acc, buf, KT) do {                                                \
  _Pragma("unroll") for (int g_ = 0; g_ < 4; ++g_)                            \
    acc[g_] = __builtin_amdgcn_mfma_f32_16x16x32_f16(                         \
        buf[g_], Bf[(KT)], acc[g_], 0, 0, 0);                                 \
} while (0)

#define PHASE4(L, acc) do {                                                   \
  const int cg_ = cgb + (L);                                                  \
  half4v hpack;                                                               \
  _Pragma("unroll") for (int r_ = 0; r_ < 4; ++r_) {                          \
    const float Be = __builtin_amdgcn_exp2f(-acc[0][r_]);                     \
    const float Ae = __builtin_amdgcn_exp2f(-acc[1][r_]);                     \
    const float De = __builtin_amdgcn_exp2f(acc[2][r_]);                      \
    const float Ee = __builtin_amdgcn_exp2f(-acc[3][r_]);                     \
    const float Ap = Ae + 1.f;                                                \
    const float Bp = Be + 1.f;                                                \
    const float Dp = De + 1.f;                                                \
    const float Nn = cst[(L) * 4 + r_] * Bp * Dp + Ap * (De - 1.f);           \
    const float cv = Nn * __builtin_amdgcn_rcpf(Ap * Bp * Dp);                \
    cst[(L) * 4 + r_] = cv;                                                   \
    const float cvc = fminf(fmaxf(cv, -10.f), 10.f);                          \
    const float Fe = __builtin_amdgcn_exp2f(K2E * cvc);                       \
    hpack[r_] = (_Float16)((Fe - 1.f) *                                       \
                __builtin_amdgcn_rcpf((Ee + 1.f) * (Fe + 1.f)));              \
  }                                                                           \
  const int lp_ = nl + 16 * (2 * (cg_ & 1) + wq_hi);                          \
  *(half4v*)&myscr[(cg_ >> 1) * 512 + lp_ * 8 + j0] = hpack;                  \
} while (0)

#define SB __builtin_amdgcn_sched_barrier(0)

// Pair-local sync: SIGNAL publishes epoch after a fence; WAITGE spins
// (lane 0) until the partner reaches the epoch, then fences.
#define SIGNAL(arr, val) do {                                                 \
  __threadfence_block();                                                      \
  if (ln == 0) arr[wv] = (val);                                               \
} while (0)
#define WAITGE(arr, val) do {                                                 \
  if (ln == 0) { while (arr[pw] < (val)) __builtin_amdgcn_s_sleep(1); }       \
  __builtin_amdgcn_wave_barrier();                                            \
  __threadfence_block();                                                      \
} while (0)

// One LSTM step (r27 form): wait partner's writes of step t-1, read Bf,
// SIGNAL flR IMMEDIATELY, then depth-2 pipelined bodies.
#define LSTM_STEP(t) do {                                                     \
  WAITGE(flW, (t));                                                           \
  half8 Bf[4];                                                                \
  _Pragma("unroll") for (int kt_ = 0; kt_ < 4; ++kt_)                         \
    Bf[kt_] = *(const half8*)&scrLane[kt_ * 512];                             \
  SIGNAL(flR, (t) + 1);                                                       \
  floatx4 accA[4], accB[4];                                                   \
  half8 Aa[4], Ab[4];                                                         \
  /* body 0 */                                                                \
  INITACC(0, accA);                                                           \
  LDA(Aa, 0, 0); LDA(Ab, 0, 1);                                               \
  MFA(accA, Aa, 0); LDA(Aa, 0, 2);                                            \
  MFA(accA, Ab, 1); LDA(Ab, 0, 3);                                            \
  MFA(accA, Aa, 2); MFA(accA, Ab, 3);                                         \
  /* body 1 */                                                                \
  INITACC(1, accB); LDA(Aa, 1, 0); LDA(Ab, 1, 1);                             \
  WAITGE(flR, (t) + 1);                                                       \
  SB; PHASE4(0, accA);                                                        \
  MFA(accB, Aa, 0); LDA(Aa, 1, 2);                                            \
  MFA(accB, Ab, 1); LDA(Ab, 1, 3);                                            \
  MFA(accB, Aa, 2); MFA(accB, Ab, 3);                                         \
  /* body 2 */                                                                \
  INITACC(2, accA); LDA(Aa, 2, 0); LDA(Ab, 2, 1);                             \
  SB; PHASE4(1, accB);                                                        \
  MFA(accA, Aa, 0); LDA(Aa, 2, 2);                                            \
  MFA(accA, Ab, 1); LDA(Ab, 2, 3);                                            \
  MFA(accA, Aa, 2); MFA(accA, Ab, 3);                                         \
  /* body 3 */                                                                \
  INITACC(3, accB); LDA(Aa, 3, 0); LDA(Ab, 3, 1);                             \
  SB; PHASE4(2, accA);                                                        \
  MFA(accB, Aa, 0); LDA(Aa, 3, 2);                                            \
  MFA(accB, Ab, 1); LDA(Ab, 3, 3);                                            \
  MFA(accB, Aa, 2); MFA(accB, Ab, 3);                                         \
  PHASE4(3, accB);                                                            \
  SIGNAL(flW, (t) + 1);                                                       \
} while (0)

// ---------------------------------------------------------------------------
// Wave-pair LSTM + hidden bucket build. Blocks 0..NBLK-1: LSTM (12 waves,
// 6 groups x 16 nodes; last block partial, reads clamped / writes guarded).
// Blocks NBLK..GRIDX-1: edge-bucket build + LDS-privatized deg.
__global__ __attribute__((amdgpu_flat_work_group_size(BTHR, BTHR),
                          amdgpu_waves_per_eu(3, 3)))
void lstm_stream_kernel(
    const float* __restrict__ xfeat, const _Float16* __restrict__ Wpack,
    const float* __restrict__ Wih, const float* __restrict__ bih,
    const float* __restrict__ bhh, _Float16* __restrict__ x1,
    const int* __restrict__ ei, const float* __restrict__ ew,
    int* __restrict__ cnt, int2* __restrict__ pairB, float* __restrict__ deg)
{
  extern __shared__ char dynlds[];
  const int tid  = threadIdx.x;   // 0..767

  if (blockIdx.x >= NBLK) {
    // ---- hidden edge-bucket build + LDS-privatized deg ----
    float* ldeg = (float*)dynlds;   // 20000 floats = 80KB (< LDS_TOTAL)
    for (int i = tid; i < N_NODES; i += BTHR) ldeg[i] = 0.f;
    __syncthreads();
    const int stride = (GRIDX - NBLK) * BTHR;
    for (int e = (blockIdx.x - NBLK) * BTHR + tid; e < N_EDGES; e += stride) {
      const int r = ei[e];
      const int c = ei[N_EDGES + e];
      const float w = ew[e];
      const int p = atomicAdd(&cnt[c], 1);
      pairB[(size_t)c * EDGE_CAP + p] = make_int2(r, __float_as_int(w));
      atomicAdd(&ldeg[c], w);   // LDS atomic: fast, block-private
    }
    __syncthreads();
    for (int i = tid; i < N_NODES; i += BTHR) {
      const float v = ldeg[i];
      if (v != 0.f) atomicAdd(&deg[i], v);
    }
    return;
  }

  _Float16* Wl  = (_Float16*)dynlds;                    // [128 tiles][64 lanes][8]
  float2*   bw  = (float2*)(dynlds + LDS_W);            // [512] (bias, wih) pre-scaled
  _Float16* scr = (_Float16*)(dynlds + LDS_W + LDS_BW); // [6][2048]
  volatile int* flR = (volatile int*)(dynlds + LDS_W + LDS_BW + LDS_SCR);
  volatile int* flW = flR + 16;

  const int wv   = tid >> 6;      // wave 0..11
  const int pw   = wv ^ 1;        // partner wave
  const int grp  = wv >> 1;       // node group 0..5
  const int role = wv & 1;        // 0: cg0-3, 1: cg4-7
  const int cgb  = role * 4;
  const int ln   = tid & 63;
  const int nl   = ln & 15;       // node within group
  const int quad = ln >> 4;
  const int n0   = blockIdx.x * NBB + grp * NBW;
  const int node  = n0 + nl;
  const int nodeC = (node < N_NODES) ? node : (N_NODES - 1);   // clamp reads

  // stage packed Whh -> LDS (coalesced float4)
  {
    const float4* src = (const float4*)Wpack;
    float4* dst = (float4*)Wl;
    for (int i = tid; i < LDS_W / 16; i += BTHR) dst[i] = src[i];
  }
  for (int i = tid; i < 512; i += BTHR) {
    const float sc = ((i >> 7) == 2) ? K2E : L2E;
    bw[i] = make_float2((bih[i] + bhh[i]) * sc, Wih[i] * sc);
  }
  {
    float4* z = (float4*)scr;
    for (int i = tid; i < LDS_SCR / 16; i += BTHR)
      z[i] = make_float4(0.f, 0.f, 0.f, 0.f);
  }
  if (tid < 32) { flR[tid] = 0; }
  __syncthreads();   // staging barrier (the only block-wide one)

  _Float16* myscr = scr + grp * 2048;
  const _Float16* WlRole  = Wl + (size_t)cgb * 2048 + (size_t)ln * 8;
  const float2*   bwRole  = bw + cgb * 16 + quad * 4;
  const _Float16* scrLane = myscr + (size_t)ln * 8;
  const float* xrow = xfeat + (size_t)nodeC * T_STEPS;

  float cst[16];
  #pragma unroll
  for (int i = 0; i < 16; ++i) cst[i] = 0.f;

  const int wq_hi = quad >> 1;
  const int j0    = (quad & 1) * 4;

  float xv = xrow[0];

  #pragma unroll 1
  for (int t = 0; t < T_STEPS; ++t) {
    const float xn = xrow[(t + 1 <= 63) ? (t + 1) : 63];
    LSTM_STEP(t);
    xv = xn;
  }

  // epilogue: each role reads only its own written banks -> no final sync.
  if (node < N_NODES) {
    #pragma unroll
    for (int k = 0; k < 2; ++k) {
      const int kt = role * 2 + k;
      half8 hf = *(const half8*)&scrLane[kt * 512];
      #pragma unroll
      for (int j = 0; j < 8; ++j)
        hf[j] = (_Float16)fmaxf((float)hf[j], 0.f);
      *(half8*)&x1[(size_t)node * HDIM + kt * 32 + quad * 8] = hf;
    }
  }
}

// ---------------------------------------------------------------------------
// FUSED middle: per block, 16 dest nodes. dinv computed on the fly from deg.
// A: bucket-aggregate x1 rows (4 dest/wave) -> z[16][132] fp16 LDS
// B: z @ gcnW^T + gcnb, relu -> zz (8 M-tiles over 4 waves)
// C: zz @ gatW^T -> xh global + att logits (12 M-tiles over 4 waves)
__global__ __launch_bounds__(256) void agg_gemm_att_kernel(
    const _Float16* __restrict__ x1, const float* __restrict__ deg,
    const int* __restrict__ cnt, const int2* __restrict__ pairB,
    const float* __restrict__ gcn_b,
    const _Float16* __restrict__ PG, const _Float16* __restrict__ PA,
    const float* __restrict__ att_src, const float* __restrict__ att_dst,
    _Float16* __restrict__ xh, float4* __restrict__ asrc,
    float4* __restrict__ adst)
{
  __shared__ float2 stg[4][64];
  __shared__ _Float16 z[16][132];
  __shared__ _Float16 zz[16][132];
  __shared__ float aS[JOUT], aD[JOUT];
  __shared__ float sAp[4][16][3], sDp[4][16][3];

  const int tid = threadIdx.x;
  const int ln = tid & 63;
  const int wv = tid >> 6;
  const int quad = ln >> 4;
  const int nl = ln & 15;
  const int nb = blockIdx.x * 16;

  for (int i = tid; i < JOUT; i += 256) { aS[i] = att_src[i]; aD[i] = att_dst[i]; }

  const half2v* x12 = (const half2v*)x1;
  // phase A: aggregate 4 dest nodes per wave (x1-space; GEMM linearity)
  #pragma unroll 1
  for (int d = 0; d < 4; ++d) {
    const int c = nb + wv * 4 + d;
    const float dc = rsqrtf(deg[c] + 1.0f);
    const half2v xc = x12[c * 64 + ln];
    float ax = (float)xc[0] * dc * dc, ay = (float)xc[1] * dc * dc; // self
    const int cc = cnt[c];
    const size_t base = (size_t)c * EDGE_CAP;
    for (int tb = 0; tb < cc; tb += 64) {
      const int ne = min(64, cc - tb);
      const int k = tb + ln;
      if (k < cc) {
        const int2 pr = pairB[base + k];
        stg[wv][ln] = make_float2(__int_as_float(pr.x),
            __int_as_float(pr.y) * rsqrtf(deg[pr.x] + 1.0f) * dc);
      }
      __builtin_amdgcn_wave_barrier();
      int i = 0;
      for (; i + 4 <= ne; i += 4) {
        float2 p0 = stg[wv][i],     p1 = stg[wv][i + 1];
        float2 p2 = stg[wv][i + 2], p3 = stg[wv][i + 3];
        const half2v a0 = x12[(size_t)__float_as_int(p0.x) * 64 + ln];
        const half2v a1 = x12[(size_t)__float_as_int(p1.x) * 64 + ln];
        const half2v a2 = x12[(size_t)__float_as_int(p2.x) * 64 + ln];
        const half2v a3 = x12[(size_t)__float_as_int(p3.x) * 64 + ln];
        ax += (float)a0[0] * p0.y + (float)a1[0] * p1.y +
              (float)a2[0] * p2.y + (float)a3[0] * p3.y;
        ay += (float)a0[1] * p0.y + (float)a1[1] * p1.y +
              (float)a2[1] * p2.y + (float)a3[1] * p3.y;
      }
      for (; i < ne; ++i) {
        float2 p0 = stg[wv][i];
        const half2v a0 = x12[(size_t)__float_as_int(p0.x) * 64 + ln];
        ax += (float)a0[0] * p0.y; ay += (float)a0[1] * p0.y;
      }
      __builtin_amdgcn_wave_barrier();
    }
    const int dn = wv * 4 + d;
    half2v o; o[0] = (_Float16)ax; o[1] = (_Float16)ay;
    *(half2v*)&z[dn][ln * 2] = o;
  }
  __syncthreads();

  // phase B: z @ gcnW^T -> relu+gcnb -> zz (wave wv: M-tiles 2wv, 2wv+1)
  {
    half8 Bf[4];
    #pragma unroll
    for (int kt = 0; kt < 4; ++kt)
      Bf[kt] = *(const half8*)&z[nl][kt * 32 + quad * 8];
    #pragma unroll
    for (int mm = 0; mm < 2; ++mm) {
      const int m = wv * 2 + mm;
      floatx4 acc = {0.f, 0.f, 0.f, 0.f};
      #pragma unroll
      for (int kt = 0; kt < 4; ++kt) {
        const half8 Af = *(const half8*)&PG[(size_t)((m * 4 + kt) * 64 + ln) * 8];
        acc = __builtin_amdgcn_mfma_f32_16x16x32_f16(Af, Bf[kt], acc, 0, 0, 0);
      }
      #pragma unroll
      for (int j = 0; j < 4; ++j) {
        const int jj = m * 16 + quad * 4 + j;
        zz[nl][jj] = (_Float16)fmaxf(acc[j] + gcn_b[jj], 0.f);
      }
    }
  }
  __syncthreads();

  // phase C: zz @ gatW^T -> xh + att partials (wave wv: M-tiles 3wv..3wv+2)
  {
    half8 Bf[4];
    #pragma unroll
    for (int kt = 0; kt < 4; ++kt)
      Bf[kt] = *(const half8*)&zz[nl][kt * 32 + quad * 8];
    float sA[3] = {0.f, 0.f, 0.f}, sD[3] = {0.f, 0.f, 0.f};
    #pragma unroll
    for (int mm = 0; mm < 3; ++mm) {
      const int m = wv * 3 + mm;
      floatx4 acc = {0.f, 0.f, 0.f, 0.f};
      #pragma unroll
      for (int kt = 0; kt < 4; ++kt) {
        const half8 Af = *(const half8*)&PA[(size_t)((m * 4 + kt) * 64 + ln) * 8];
        acc = __builtin_amdgcn_mfma_f32_16x16x32_f16(Af, Bf[kt], acc, 0, 0, 0);
      }
      const int h  = m >> 2;
      const int jo = (m & 3) * 16 + quad * 4;
      half4v o;
      #pragma unroll
      for (int j = 0; j < 4; ++j) {
        sA[h] += acc[j] * aS[h * 64 + jo + j];
        sD[h] += acc[j] * aD[h * 64 + jo + j];
        o[j] = (_Float16)acc[j];
      }
      *(half4v*)&xh[(size_t)(nb + nl) * JOUT + m * 16 + quad * 4] = o;
    }
    #pragma unroll
    for (int h = 0; h < 3; ++h) {
      sA[h] += __shfl_xor(sA[h], 16); sA[h] += __shfl_xor(sA[h], 32);
      sD[h] += __shfl_xor(sD[h], 16); sD[h] += __shfl_xor(sD[h], 32);
    }
    if (quad == 0) {
      #pragma unroll
      for (int h = 0; h < 3; ++h) {
        sAp[wv][nl][h] = sA[h];
        sDp[wv][nl][h] = sD[h];
      }
    }
  }
  __syncthreads();
  if (tid < 16) {
    float a0 = 0.f, a1 = 0.f, a2 = 0.f, d0 = 0.f, d1 = 0.f, d2 = 0.f;
    #pragma unroll
    for (int w = 0; w < 4; ++w) {
      a0 += sAp[w][tid][0]; a1 += sAp[w][tid][1]; a2 += sAp[w][tid][2];
      d0 += sDp[w][tid][0]; d1 += sDp[w][tid][1]; d2 += sDp[w][tid][2];
    }
    asrc[nb + tid] = make_float4(a0, a1, a2, 0.f);
    adst[nb + tid] = make_float4(d0, d1, d2, 0.f);
  }
}

// ---------------------------------------------------------------------------
// GAT softmax weights (mean-trick): one wave per destination c. Computes
// denom_c per head (single-pass, no max-sub; logits |.|<~4), then scatters
// alpha/denom into per-SOURCE weight sums W[s][h] (+ self term to W[c]).
__global__ __launch_bounds__(256) void gat_weight_kernel(
    const float4* __restrict__ asrc, const float4* __restrict__ adst,
    const int* __restrict__ cnt, const int2* __restrict__ pairB,
    float* __restrict__ W)
{
  const int lane = threadIdx.x & 63;
  const int wv = threadIdx.x >> 6;
  const int c = blockIdx.x * 4 + wv;
  const int cc = cnt[c];
  const size_t base = (size_t)c * EDGE_CAP;
  const float4 adc = adst[c];
  const float4 asc = asrc[c];
  const float se0 = __expf(lrelu(asc.x + adc.x));
  const float se1 = __expf(lrelu(asc.y + adc.y));
  const float se2 = __expf(lrelu(asc.z + adc.z));
  float dp0 = 0.f, dp1 = 0.f, dp2 = 0.f;
  float a0v[2], a1v[2], a2v[2]; int sv[2];
  #pragma unroll
  for (int it = 0; it < 2; ++it) {
    const int k = it * 64 + lane;
    sv[it] = -1;
    a0v[it] = 0.f; a1v[it] = 0.f; a2v[it] = 0.f;
    if (k < cc) {
      const int s = pairB[base + k].x;
      const float4 av = asrc[s];
      const float a0 = __expf(lrelu(av.x + adc.x));
      const float a1 = __expf(lrelu(av.y + adc.y));
      const float a2 = __expf(lrelu(av.z + adc.z));
      dp0 += a0; dp1 += a1; dp2 += a2;
      sv[it] = s; a0v[it] = a0; a1v[it] = a1; a2v[it] = a2;
    }
  }
  #pragma unroll
  for (int off = 1; off < 64; off <<= 1) {
    dp0 += __shfl_xor(dp0, off);
    dp1 += __shfl_xor(dp1, off);
    dp2 += __shfl_xor(dp2, off);
  }
  const float iv0 = 1.f / (dp0 + se0);
  const float iv1 = 1.f / (dp1 + se1);
  const float iv2 = 1.f / (dp2 + se2);
  if (lane == 0) {
    atomicAdd(&W[c * 4 + 0], se0 * iv0);
    atomicAdd(&W[c * 4 + 1], se1 * iv1);
    atomicAdd(&W[c * 4 + 2], se2 * iv2);
  }
  #pragma unroll
  for (int it = 0; it < 2; ++it) {
    if (sv[it] >= 0) {
      atomicAdd(&W[sv[it] * 4 + 0], a0v[it] * iv0);
      atomicAdd(&W[sv[it] * 4 + 1], a1v[it] * iv1);
      atomicAdd(&W[sv[it] * 4 + 2], a2v[it] * iv2);
    }
  }
}

// Final coalesced sweep: accum[j] += sum_s W[s][h] * xh[s][j].
__global__ __launch_bounds__(192) void gat_final_kernel(
    const _Float16* __restrict__ xh, const float* __restrict__ W,
    float* __restrict__ accum)
{
  const int j = threadIdx.x;          // 0..191
  const int h = j >> 6;
  float sum = 0.f;
  const int s0 = blockIdx.x * 80;
  for (int s = s0; s < s0 + 80; ++s)
    sum += W[s * 4 + h] * (float)xh[(size_t)s * JOUT + j];
  atomicAdd(&accum[j], sum);
}

__global__ void finalize_kernel(const float* __restrict__ accum,
                                const float* __restrict__ gat_b,
                                float* __restrict__ out)
{
  int j = threadIdx.x;
  if (j < JOUT) out[j] = accum[j] * (1.0f / N_NODES) + gat_b[j];
}

// ---------------------------------------------------------------------------
extern "C" void kernel_launch(void* const* d_in, const int* in_sizes, int n_in,
                              void* d_out, int out_size, void* d_ws, size_t ws_size,
                              hipStream_t stream)
{
  const float* xfeat = (const float*)d_in[0];
  const int*   eidx  = (const int*)d_in[1];
  const float* eattr = (const float*)d_in[2];
  const float* Wih   = (const float*)d_in[3];
  const float* Whh   = (const float*)d_in[4];
  const float* bihp  = (const float*)d_in[5];
  const float* bhhp  = (const float*)d_in[6];
  const float* gcnW  = (const float*)d_in[7];
  const float* gcnb  = (const float*)d_in[8];
  const float* gatW  = (const float*)d_in[9];
  const float* attS  = (const float*)d_in[10];
  const float* attD  = (const float*)d_in[11];
  const float* gatb  = (const float*)d_in[12];
  float* out = (float*)d_out;

  char* ws = (char*)d_ws;
  size_t off = 0;
  auto alloc = [&](size_t bytes) {
    char* p = ws + off;
    off += (bytes + 255) & ~size_t(255);
    return p;
  };
  _Float16*  x1     = (_Float16*)alloc((size_t)N_NODES * 128 * 2);
  _Float16*  xh     = (_Float16*)alloc((size_t)N_NODES * 192 * 2);
  float4*    asrc   = (float4*)alloc((size_t)N_NODES * 16);
  float4*    adst   = (float4*)alloc((size_t)N_NODES * 16);
  float*     deg    = (float*)alloc((size_t)N_NODES * 4);
  int*       cnt    = (int*)alloc((size_t)N_NODES * 4);
  int2*      pairB  = (int2*)alloc((size_t)N_NODES * EDGE_CAP * 8);
  float*     Wgt    = (float*)alloc((size_t)N_NODES * 4 * 4);
  float*     accum  = (float*)alloc(JOUT * 4);
  _Float16*  wpack  = (_Float16*)alloc(131072);
  _Float16*  wpackG = (_Float16*)alloc((size_t)128 * 128 * 2);
  _Float16*  wpackA = (_Float16*)alloc((size_t)192 * 128 * 2);

  // opt-in to >64KB dynamic LDS for the wave-pair LSTM (idempotent)
  hipFuncSetAttribute((const void*)lstm_stream_kernel,
                      hipFuncAttributeMaxDynamicSharedMemorySize, LDS_TOTAL);

  prep_kernel<<<131, 256, 0, stream>>>(Whh, wpack, gcnW, wpackG, gatW, wpackA,
                                       cnt, deg, Wgt, accum);
  // LSTM (blocks 0..208) + hidden edge-bucket+deg build (blocks 209..214)
  lstm_stream_kernel<<<GRIDX, BTHR, LDS_TOTAL, stream>>>(
      xfeat, wpack, Wih, bihp, bhhp, x1, eidx, eattr, cnt, pairB, deg);
  agg_gemm_att_kernel<<<N_NODES / 16, 256, 0, stream>>>(
      x1, deg, cnt, pairB, gcnb, wpackG, wpackA, attS, attD, xh, asrc, adst);
  gat_weight_kernel<<<N_NODES / 4, 256, 0, stream>>>(asrc, adst, cnt, pairB, Wgt);
  gat_final_kernel<<<N_NODES / 80, 192, 0, stream>>>(xh, Wgt, accum);
  finalize_kernel<<<1, 256, 0, stream>>>(accum, gatb, out);
}